// Round 5
// baseline (547.489 us; speedup 1.0000x reference)
//
#include <hip/hip_runtime.h>
#include <float.h>

#define BATCH 4
#define LSEQ  2048
#define DMODEL 512
#define NH    8
#define DHD   64
#define NSAMP 40
#define NTOP  40
#define NCHUNK 32
#define TK    64                 // keys per attn chunk
#define QK_SCALE 0.125f          // 1/sqrt(64)

// ---------------------------------------------------------------------------
// K1: fp32 QKV GEMM (vector ALU — no fp32 MFMA on CDNA4; M-selection needs
// fp32-exact Q/K).  C = A @ W^T + b.
// v3: tile 128x64, 8x4 micro-tile, grid (64,8,3) = 1536 blocks = 6 blocks/CU
// (was 3/CU — stall-bound). LDS 25.6 KB. One head per block.
// ---------------------------------------------------------------------------
#define KSTEP 32

__global__ __launch_bounds__(256, 5) void qkv_gemm_f32(
    const float* __restrict__ x, const float* __restrict__ ctxin,
    const float* __restrict__ Wq, const float* __restrict__ bq,
    const float* __restrict__ Wk, const float* __restrict__ bk,
    const float* __restrict__ Wv, const float* __restrict__ bv,
    float* __restrict__ Qt, float* __restrict__ Kt, float* __restrict__ Vt)
{
    const int z = blockIdx.z;
    const float* __restrict__ A    = (z == 0) ? x  : ctxin;
    const float* __restrict__ W    = (z == 0) ? Wq : (z == 1 ? Wk : Wv);
    const float* __restrict__ bias = (z == 0) ? bq : (z == 1 ? bk : bv);
    float*       __restrict__ Out  = (z == 0) ? Qt : (z == 1 ? Kt : Vt);

    __shared__ float As[KSTEP][128 + 4];   // [k][m] 16896 B
    __shared__ float Ws2[KSTEP][64 + 4];   // [k][n]  8704 B

    const int tid = threadIdx.x;
    const int tn  = tid & 15;            // n-group: 4 cols
    const int tm  = tid >> 4;            // m-group: 8 rows
    const int m0  = blockIdx.x * 128;
    const int n0  = blockIdx.y * 64;
    const int h   = blockIdx.y;          // n0>>6

    const int srow = tid >> 3;           // 0..31
    const int sc4  = tid & 7;            // 0..7

    float acc[8][4] = {};
    float4 ar[4], wr[2];

    // prologue: tile-0 loads
#pragma unroll
    for (int rr = 0; rr < 4; ++rr)
        ar[rr] = *reinterpret_cast<const float4*>(A + (size_t)(m0 + srow + rr * 32) * DMODEL + sc4 * 4);
#pragma unroll
    for (int rr = 0; rr < 2; ++rr)
        wr[rr] = *reinterpret_cast<const float4*>(W + (size_t)(n0 + srow + rr * 32) * DMODEL + sc4 * 4);

    for (int k0 = 0; k0 < DMODEL; k0 += KSTEP) {
        // staged regs -> LDS (transposed)
#pragma unroll
        for (int rr = 0; rr < 4; ++rr) {
            const int r = srow + rr * 32;
            As[sc4 * 4 + 0][r] = ar[rr].x; As[sc4 * 4 + 1][r] = ar[rr].y;
            As[sc4 * 4 + 2][r] = ar[rr].z; As[sc4 * 4 + 3][r] = ar[rr].w;
        }
#pragma unroll
        for (int rr = 0; rr < 2; ++rr) {
            const int r = srow + rr * 32;
            Ws2[sc4 * 4 + 0][r] = wr[rr].x; Ws2[sc4 * 4 + 1][r] = wr[rr].y;
            Ws2[sc4 * 4 + 2][r] = wr[rr].z; Ws2[sc4 * 4 + 3][r] = wr[rr].w;
        }
        __syncthreads();

        // prefetch next tile (latency hides under compute)
        if (k0 + KSTEP < DMODEL) {
#pragma unroll
            for (int rr = 0; rr < 4; ++rr)
                ar[rr] = *reinterpret_cast<const float4*>(
                    A + (size_t)(m0 + srow + rr * 32) * DMODEL + k0 + KSTEP + sc4 * 4);
#pragma unroll
            for (int rr = 0; rr < 2; ++rr)
                wr[rr] = *reinterpret_cast<const float4*>(
                    W + (size_t)(n0 + srow + rr * 32) * DMODEL + k0 + KSTEP + sc4 * 4);
        }

#pragma unroll
        for (int kk = 0; kk < KSTEP; ++kk) {
            float a[8], b[4];
            *reinterpret_cast<float4*>(&a[0]) =
                *reinterpret_cast<const float4*>(&As[kk][tm * 8]);
            *reinterpret_cast<float4*>(&a[4]) =
                *reinterpret_cast<const float4*>(&As[kk][tm * 8 + 4]);
            *reinterpret_cast<float4*>(&b[0]) =
                *reinterpret_cast<const float4*>(&Ws2[kk][tn * 4]);
#pragma unroll
            for (int i = 0; i < 8; ++i)
#pragma unroll
                for (int j = 0; j < 4; ++j)
                    acc[i][j] = fmaf(a[i], b[j], acc[i][j]);
        }
        __syncthreads();
    }

    const float4 bi = *reinterpret_cast<const float4*>(bias + n0 + tn * 4);
#pragma unroll
    for (int i = 0; i < 8; ++i) {
        const int m = m0 + tm * 8 + i;
        const int b = m >> 11, l = m & (LSEQ - 1);
        float4 o;
        o.x = acc[i][0] + bi.x; o.y = acc[i][1] + bi.y;
        o.z = acc[i][2] + bi.z; o.w = acc[i][3] + bi.w;
        *reinterpret_cast<float4*>(
            Out + (((size_t)(b * NH + h) * LSEQ) + l) * DHD + tn * 4) = o;
    }
}

// ---------------------------------------------------------------------------
// K2: sampled sparsity measure + zero-init of headmask/VmeanRaw (replaces two
// memset dispatches; runs before their consumers topk/attn_partial).
// ---------------------------------------------------------------------------
__global__ __launch_bounds__(256) void score_kernel(
    const float* __restrict__ Qt, const float* __restrict__ Kt,
    const int* __restrict__ idxs, float* __restrict__ M,
    unsigned* __restrict__ headmask, float* __restrict__ VmeanRaw)
{
    const int flat = blockIdx.x;             // 16384 blocks
    if (flat < 32) headmask[flat * 256 + threadIdx.x] = 0u;
    else if (flat < 40) VmeanRaw[(flat - 32) * 256 + threadIdx.x] = 0.f;

    const int xcd  = flat & 7;
    const int slot = flat >> 3;              // 0..2047
    const int bh   = xcd * 4 + (slot >> 9);  // 4 bh per XCD
    const int w    = threadIdx.x >> 6;
    const int lane = threadIdx.x & 63;
    const int l    = (slot & 511) * 4 + w;

    __shared__ float qs[4][DHD];
    qs[w][lane] = Qt[((size_t)bh * LSEQ + l) * DHD + lane];  // wave-local RAW

    float acc = 0.f;
    if (lane < NSAMP) {
        const int ks = idxs[l * NSAMP + lane];
        const float4* kr = reinterpret_cast<const float4*>(
            Kt + ((size_t)bh * LSEQ + ks) * DHD);
#pragma unroll
        for (int j = 0; j < 16; ++j) {
            const float4 kv = kr[j];
            acc += qs[w][j * 4 + 0] * kv.x + qs[w][j * 4 + 1] * kv.y +
                   qs[w][j * 4 + 2] * kv.z + qs[w][j * 4 + 3] * kv.w;
        }
    }
    float vmax = (lane < NSAMP) ? acc : -FLT_MAX;
    float vsum = (lane < NSAMP) ? acc : 0.f;
#pragma unroll
    for (int off = 32; off; off >>= 1) {
        vmax = fmaxf(vmax, __shfl_xor(vmax, off));
        vsum += __shfl_xor(vsum, off);
    }
    if (lane == 0) M[(size_t)bh * LSEQ + l] = vmax - vsum * (1.0f / LSEQ);
}

// ---------------------------------------------------------------------------
// K3: stable top-40 per (b,h); candidates in registers.
// ---------------------------------------------------------------------------
__global__ __launch_bounds__(256) void topk_kernel(
    const float* __restrict__ M, int* __restrict__ topidx,
    unsigned* __restrict__ headmask, unsigned char* __restrict__ slot)
{
    const int bh = blockIdx.x;
    const int b = bh >> 3, h = bh & 7;
    const int w = threadIdx.x >> 6, lane = threadIdx.x & 63;
    const int base = threadIdx.x * 8;

    float e[8];
    {
        const float4 v0 = *reinterpret_cast<const float4*>(M + (size_t)bh * LSEQ + base);
        const float4 v1 = *reinterpret_cast<const float4*>(M + (size_t)bh * LSEQ + base + 4);
        e[0] = v0.x; e[1] = v0.y; e[2] = v0.z; e[3] = v0.w;
        e[4] = v1.x; e[5] = v1.y; e[6] = v1.z; e[7] = v1.w;
    }

    __shared__ float rv[4];
    __shared__ int   ri[4];
    __shared__ int   winner;

    for (int t = 0; t < NTOP; ++t) {
        float bv = e[0]; int br = 0;
#pragma unroll
        for (int r = 1; r < 8; ++r)
            if (e[r] > bv) { bv = e[r]; br = r; }    // strict >: smallest r on tie
        int bi = base + br;
#pragma unroll
        for (int off = 32; off; off >>= 1) {
            const float ov = __shfl_xor(bv, off);
            const int   oi = __shfl_xor(bi, off);
            if (ov > bv || (ov == bv && oi < bi)) { bv = ov; bi = oi; }
        }
        if (lane == 0) { rv[w] = bv; ri[w] = bi; }
        __syncthreads();
        if (threadIdx.x == 0) {
            float fv = rv[0]; int fi = ri[0];
#pragma unroll
            for (int k = 1; k < 4; ++k)
                if (rv[k] > fv || (rv[k] == fv && ri[k] < fi)) { fv = rv[k]; fi = ri[k]; }
            topidx[bh * NTOP + t] = fi;
            atomicOr(&headmask[b * LSEQ + fi], 1u << h);
            slot[bh * LSEQ + fi] = (unsigned char)t;
            winner = fi;
        }
        __syncthreads();
        const int fi = winner;
        if ((fi >> 3) == threadIdx.x) e[fi & 7] = -FLT_MAX;
    }
}

// ---------------------------------------------------------------------------
// K4: flash split-K attention partials + V column-sum accumulation (vmean
// folded in — V is already staged here; saves a separate 32 MB pass).
// Score phase remapped (k in lane-low bits) -> 2-way/broadcast LDS banks.
// ---------------------------------------------------------------------------
__global__ __launch_bounds__(256) void attn_partial(
    const float* __restrict__ Qt, const float* __restrict__ Kt,
    const float* __restrict__ Vt, const int* __restrict__ topidx,
    float* __restrict__ psums, float* __restrict__ pacc,
    float* __restrict__ VmeanRaw)
{
    const int bh = blockIdx.x;
    const int c  = blockIdx.y;
    const int kbase = c * TK;
    const int tid = threadIdx.x;

    __shared__ float Qs[NTOP][DHD];
    __shared__ float Ks[TK][68];
    __shared__ float Vs[TK][68];
    __shared__ float Sc[TK][52];

    for (int i = tid; i < NTOP * DHD; i += 256) {
        const int q = i >> 6, d = i & 63;
        const int row = topidx[bh * NTOP + q];
        Qs[q][d] = Qt[((size_t)bh * LSEQ + row) * DHD + d];
    }
    {
        const int r0 = tid >> 4, c4 = tid & 15;
#pragma unroll
        for (int rr = 0; rr < 4; ++rr) {
            const int r = r0 + rr * 16;
            const size_t g = ((size_t)bh * LSEQ + kbase + r) * DHD + c4 * 4;
            *reinterpret_cast<float4*>(&Ks[r][c4 * 4]) =
                *reinterpret_cast<const float4*>(Kt + g);
            *reinterpret_cast<float4*>(&Vs[r][c4 * 4]) =
                *reinterpret_cast<const float4*>(Vt + g);
        }
    }
    __syncthreads();

    // V column partial sums (vmean fold-in)
    {
        const int d = tid & 63, part = tid >> 6;
        float s = 0.f;
#pragma unroll
        for (int i = 0; i < 16; ++i) s += Vs[part * 16 + i][d];
        atomicAdd(&VmeanRaw[bh * DHD + d], s);
    }

    // scores: thread -> (kloc = tid&15, qg = tid>>4); Ks reads 2-way/broadcast
    {
        const int kloc = tid & 15, qg = tid >> 4;
#pragma unroll
        for (int qit = 0; qit < 3; ++qit) {
            const int q = qg + qit * 16;
            if (q < NTOP) {
#pragma unroll
                for (int kb = 0; kb < 4; ++kb) {
                    const int k = kloc + kb * 16;
                    float acc = 0.f;
#pragma unroll
                    for (int j = 0; j < 16; ++j) {
                        const float4 kv = *reinterpret_cast<const float4*>(&Ks[k][j * 4]);
                        const float4 qv = *reinterpret_cast<const float4*>(&Qs[q][j * 4]);
                        acc += qv.x * kv.x + qv.y * kv.y + qv.z * kv.z + qv.w * kv.w;
                    }
                    Sc[k][q] = acc * QK_SCALE;
                }
            }
        }
    }
    __syncthreads();

    // exp + per-chunk partial sums. exp w/o max-subtraction: scores O(+-8),
    // fp32 exp overflows only past 88 — mathematically identical result.
    {
        const int w = tid >> 6, lane = tid & 63;
#pragma unroll
        for (int j = 0; j < 10; ++j) {
            const int q = w * 10 + j;
            const float ee = __expf(Sc[lane][q]);
            float s = ee;
#pragma unroll
            for (int off = 32; off; off >>= 1) s += __shfl_xor(s, off);
            Sc[lane][q] = ee;
            if (lane == 0) psums[((size_t)bh * NCHUNK + c) * NTOP + q] = s;
        }
    }
    __syncthreads();

    // partial PV
    {
        const int d = tid & 63, g = tid >> 6;
        const int q0 = g * 12;
        const int nq = (g < 3) ? 12 : 4;
        float acc[12] = {};
        for (int k = 0; k < TK; ++k) {
            const float v = Vs[k][d];
            const float4 s0 = *reinterpret_cast<const float4*>(&Sc[k][q0]);
            acc[0] = fmaf(s0.x, v, acc[0]); acc[1] = fmaf(s0.y, v, acc[1]);
            acc[2] = fmaf(s0.z, v, acc[2]); acc[3] = fmaf(s0.w, v, acc[3]);
            if (g < 3) {
                const float4 s1 = *reinterpret_cast<const float4*>(&Sc[k][q0 + 4]);
                const float4 s2 = *reinterpret_cast<const float4*>(&Sc[k][q0 + 8]);
                acc[4] = fmaf(s1.x, v, acc[4]); acc[5]  = fmaf(s1.y, v, acc[5]);
                acc[6] = fmaf(s1.z, v, acc[6]); acc[7]  = fmaf(s1.w, v, acc[7]);
                acc[8] = fmaf(s2.x, v, acc[8]); acc[9]  = fmaf(s2.y, v, acc[9]);
                acc[10] = fmaf(s2.z, v, acc[10]); acc[11] = fmaf(s2.w, v, acc[11]);
            }
        }
#pragma unroll
        for (int j = 0; j < 12; ++j)
            if (j < nq)
                pacc[(((size_t)bh * NCHUNK + c) * NTOP + q0 + j) * DHD + d] = acc[j];
    }
}

// ---------------------------------------------------------------------------
// K5: combine partials -> delta = upd - Vmean; blocks with bh%8==0 also
// compute the per-batch mean output row (meanout fold-in).
// ---------------------------------------------------------------------------
__global__ __launch_bounds__(256) void attn_combine(
    const float* __restrict__ psums, const float* __restrict__ pacc,
    const float* __restrict__ VmeanRaw, const float* __restrict__ Wo,
    const float* __restrict__ bo, float* __restrict__ delta,
    float* __restrict__ meanout)
{
    const int bh = blockIdx.x;
    __shared__ float winv[NTOP];
    __shared__ float mc[DMODEL];
    if (threadIdx.x < NTOP) {
        float s = 0.f;
        for (int c = 0; c < NCHUNK; ++c)
            s += psums[((size_t)bh * NCHUNK + c) * NTOP + threadIdx.x];
        winv[threadIdx.x] = 1.0f / s;
    }
    __syncthreads();
    const int d = threadIdx.x & 63, g = threadIdx.x >> 6;
    const float vm = VmeanRaw[bh * DHD + d] * (1.0f / (float)LSEQ);
    for (int q = g; q < NTOP; q += 4) {
        float a = 0.f;
        for (int c = 0; c < NCHUNK; ++c)
            a += pacc[(((size_t)bh * NCHUNK + c) * NTOP + q) * DHD + d];
        delta[((size_t)bh * NTOP + q) * DHD + d] = a * winv[q] - vm;
    }

    if ((bh & 7) == 0) {               // block-uniform branch: barriers legal
        const int b = bh >> 3;
        for (int i = threadIdx.x; i < DMODEL; i += 256)
            mc[i] = VmeanRaw[b * DMODEL + i] * (1.0f / (float)LSEQ);
        __syncthreads();
        for (int n = threadIdx.x; n < DMODEL; n += 256) {
            float acc = bo[n];
            const float* wr = Wo + (size_t)n * DMODEL;
            for (int k = 0; k < DMODEL; ++k) acc = fmaf(mc[k], wr[k], acc);
            meanout[b * DMODEL + n] = acc;
        }
    }
}

// ---------------------------------------------------------------------------
// K6: final output rows; 128 threads, float4 path.
// ---------------------------------------------------------------------------
__global__ __launch_bounds__(128) void out_kernel(
    const float* __restrict__ meanout, const unsigned* __restrict__ headmask,
    const unsigned char* __restrict__ slot, const float* __restrict__ delta,
    const float* __restrict__ Wo, float* __restrict__ out)
{
    const int rowg = blockIdx.x;
    const int b = rowg >> 11, lloc = rowg & (LSEQ - 1);
    const unsigned mask = headmask[rowg];

    __shared__ float dl[NH][DHD];
    if (threadIdx.x < DHD) {
        for (int h = 0; h < NH; ++h) {
            if ((mask >> h) & 1) {
                const int bh = b * NH + h;
                const int u = slot[bh * LSEQ + lloc];
                dl[h][threadIdx.x] = delta[((size_t)bh * NTOP + u) * DHD + threadIdx.x];
            }
        }
    }
    __syncthreads();

    const int n4 = threadIdx.x;           // 0..127 float4-chunks of 512
    float4 val = *reinterpret_cast<const float4*>(meanout + b * DMODEL + n4 * 4);
    unsigned mm = mask;
    while (mm) {
        const int h = __ffs(mm) - 1;
        mm &= mm - 1;
#pragma unroll
        for (int c = 0; c < 4; ++c) {
            const int n = n4 * 4 + c;
            const float4* wr4 = reinterpret_cast<const float4*>(
                Wo + (size_t)n * DMODEL + h * DHD);
            float a = 0.f;
#pragma unroll
            for (int dd = 0; dd < 16; ++dd) {
                const float4 wv = wr4[dd];
                a += dl[h][dd * 4 + 0] * wv.x + dl[h][dd * 4 + 1] * wv.y +
                     dl[h][dd * 4 + 2] * wv.z + dl[h][dd * 4 + 3] * wv.w;
            }
            (&val.x)[c] += a;
        }
    }
    *reinterpret_cast<float4*>(out + (size_t)rowg * DMODEL + n4 * 4) = val;
}

// ---------------------------------------------------------------------------
extern "C" void kernel_launch(void* const* d_in, const int* in_sizes, int n_in,
                              void* d_out, int out_size, void* d_ws, size_t ws_size,
                              hipStream_t stream)
{
    (void)in_sizes; (void)n_in; (void)out_size; (void)ws_size;
    const float* x     = (const float*)d_in[0];
    const float* ctxin = (const float*)d_in[1];
    const float* Wq    = (const float*)d_in[2];
    const float* bq    = (const float*)d_in[3];
    const float* Wk    = (const float*)d_in[4];
    const float* bk    = (const float*)d_in[5];
    const float* Wv    = (const float*)d_in[6];
    const float* bv    = (const float*)d_in[7];
    const float* Wo    = (const float*)d_in[8];
    const float* bo    = (const float*)d_in[9];
    const int*   idxs  = (const int*)d_in[10];
    float* out = (float*)d_out;

    char* ws = (char*)d_ws;
    size_t off = 0;
    auto alloc = [&](size_t bytes) -> void* {
        void* p = ws + off;
        off += (bytes + 255) & ~(size_t)255;
        return p;
    };

    const size_t qkv_bytes = (size_t)BATCH * NH * LSEQ * DHD * sizeof(float);
    float*         Qt       = (float*)alloc(qkv_bytes);
    float*         Kt       = (float*)alloc(qkv_bytes);
    float*         Vt       = (float*)alloc(qkv_bytes);
    float*         Mbuf     = (float*)alloc((size_t)BATCH * NH * LSEQ * sizeof(float));
    float*         VmeanRaw = (float*)alloc((size_t)BATCH * NH * DHD * sizeof(float));
    float*         meanout  = (float*)alloc((size_t)BATCH * DMODEL * sizeof(float));
    float*         delta    = (float*)alloc((size_t)BATCH * NH * NTOP * DHD * sizeof(float));
    int*           topidx   = (int*)alloc((size_t)BATCH * NH * NTOP * sizeof(int));
    unsigned*      headmask = (unsigned*)alloc((size_t)BATCH * LSEQ * sizeof(unsigned));
    unsigned char* slot     = (unsigned char*)alloc((size_t)BATCH * NH * LSEQ);
    float*         psums    = (float*)alloc((size_t)BATCH * NH * NCHUNK * NTOP * sizeof(float));
    float*         pacc     = (float*)alloc((size_t)BATCH * NH * NCHUNK * NTOP * DHD * sizeof(float));

    qkv_gemm_f32<<<dim3(8192 / 128, DMODEL / 64, 3), 256, 0, stream>>>(
        x, ctxin, Wq, bq, Wk, bk, Wv, bv, Qt, Kt, Vt);

    score_kernel<<<(BATCH * NH * LSEQ) / 4, 256, 0, stream>>>(
        Qt, Kt, idxs, Mbuf, headmask, VmeanRaw);

    topk_kernel<<<BATCH * NH, 256, 0, stream>>>(Mbuf, topidx, headmask, slot);

    attn_partial<<<dim3(BATCH * NH, NCHUNK), 256, 0, stream>>>(
        Qt, Kt, Vt, topidx, psums, pacc, VmeanRaw);

    attn_combine<<<BATCH * NH, 256, 0, stream>>>(
        psums, pacc, VmeanRaw, Wo, bo, delta, meanout);

    out_kernel<<<BATCH * LSEQ, 128, 0, stream>>>(
        meanout, headmask, slot, delta, Wo, out);
}

// Round 6
// 458.710 us; speedup vs baseline: 1.1935x; 1.1935x over previous
//
#include <hip/hip_runtime.h>
#include <float.h>

#define BATCH 4
#define LSEQ  2048
#define DMODEL 512
#define NH    8
#define DHD   64
#define NSAMP 40
#define NTOP  40
#define NCHUNK 32
#define TK    64                 // keys per attn chunk
#define QK_SCALE 0.125f          // 1/sqrt(64)

// ---------------------------------------------------------------------------
// K1: fp32 QKV GEMM (vector ALU — no fp32 MFMA on CDNA4; M-selection needs
// fp32-exact Q/K).  C = A @ W^T + b.
// v4: tile 128x64, 8x4 micro-tile, grid (64,8,3) = 1536 blocks, 25.6 KB LDS.
// NO min-waves clamp: round-5's (256,5) forced VGPR=48 -> accumulator spill
// (FETCH 36->333MB, WRITE 615MB). Natural allocation ~90-116 VGPR -> 4-5
// blocks/CU, no scratch.
// ---------------------------------------------------------------------------
#define KSTEP 32

__global__ __launch_bounds__(256) void qkv_gemm_f32(
    const float* __restrict__ x, const float* __restrict__ ctxin,
    const float* __restrict__ Wq, const float* __restrict__ bq,
    const float* __restrict__ Wk, const float* __restrict__ bk,
    const float* __restrict__ Wv, const float* __restrict__ bv,
    float* __restrict__ Qt, float* __restrict__ Kt, float* __restrict__ Vt)
{
    const int z = blockIdx.z;
    const float* __restrict__ A    = (z == 0) ? x  : ctxin;
    const float* __restrict__ W    = (z == 0) ? Wq : (z == 1 ? Wk : Wv);
    const float* __restrict__ bias = (z == 0) ? bq : (z == 1 ? bk : bv);
    float*       __restrict__ Out  = (z == 0) ? Qt : (z == 1 ? Kt : Vt);

    __shared__ float As[KSTEP][128 + 4];   // [k][m] 16896 B
    __shared__ float Ws2[KSTEP][64 + 4];   // [k][n]  8704 B

    const int tid = threadIdx.x;
    const int tn  = tid & 15;            // n-group: 4 cols
    const int tm  = tid >> 4;            // m-group: 8 rows
    const int m0  = blockIdx.x * 128;
    const int n0  = blockIdx.y * 64;
    const int h   = blockIdx.y;          // n0>>6

    const int srow = tid >> 3;           // 0..31
    const int sc4  = tid & 7;            // 0..7

    float acc[8][4] = {};
    float4 ar[4], wr[2];

    // prologue: tile-0 loads
#pragma unroll
    for (int rr = 0; rr < 4; ++rr)
        ar[rr] = *reinterpret_cast<const float4*>(A + (size_t)(m0 + srow + rr * 32) * DMODEL + sc4 * 4);
#pragma unroll
    for (int rr = 0; rr < 2; ++rr)
        wr[rr] = *reinterpret_cast<const float4*>(W + (size_t)(n0 + srow + rr * 32) * DMODEL + sc4 * 4);

    for (int k0 = 0; k0 < DMODEL; k0 += KSTEP) {
        // staged regs -> LDS (transposed)
#pragma unroll
        for (int rr = 0; rr < 4; ++rr) {
            const int r = srow + rr * 32;
            As[sc4 * 4 + 0][r] = ar[rr].x; As[sc4 * 4 + 1][r] = ar[rr].y;
            As[sc4 * 4 + 2][r] = ar[rr].z; As[sc4 * 4 + 3][r] = ar[rr].w;
        }
#pragma unroll
        for (int rr = 0; rr < 2; ++rr) {
            const int r = srow + rr * 32;
            Ws2[sc4 * 4 + 0][r] = wr[rr].x; Ws2[sc4 * 4 + 1][r] = wr[rr].y;
            Ws2[sc4 * 4 + 2][r] = wr[rr].z; Ws2[sc4 * 4 + 3][r] = wr[rr].w;
        }
        __syncthreads();

        // prefetch next tile (latency hides under compute)
        if (k0 + KSTEP < DMODEL) {
#pragma unroll
            for (int rr = 0; rr < 4; ++rr)
                ar[rr] = *reinterpret_cast<const float4*>(
                    A + (size_t)(m0 + srow + rr * 32) * DMODEL + k0 + KSTEP + sc4 * 4);
#pragma unroll
            for (int rr = 0; rr < 2; ++rr)
                wr[rr] = *reinterpret_cast<const float4*>(
                    W + (size_t)(n0 + srow + rr * 32) * DMODEL + k0 + KSTEP + sc4 * 4);
        }

#pragma unroll
        for (int kk = 0; kk < KSTEP; ++kk) {
            float a[8], b[4];
            *reinterpret_cast<float4*>(&a[0]) =
                *reinterpret_cast<const float4*>(&As[kk][tm * 8]);
            *reinterpret_cast<float4*>(&a[4]) =
                *reinterpret_cast<const float4*>(&As[kk][tm * 8 + 4]);
            *reinterpret_cast<float4*>(&b[0]) =
                *reinterpret_cast<const float4*>(&Ws2[kk][tn * 4]);
#pragma unroll
            for (int i = 0; i < 8; ++i)
#pragma unroll
                for (int j = 0; j < 4; ++j)
                    acc[i][j] = fmaf(a[i], b[j], acc[i][j]);
        }
        __syncthreads();
    }

    const float4 bi = *reinterpret_cast<const float4*>(bias + n0 + tn * 4);
#pragma unroll
    for (int i = 0; i < 8; ++i) {
        const int m = m0 + tm * 8 + i;
        const int b = m >> 11, l = m & (LSEQ - 1);
        float4 o;
        o.x = acc[i][0] + bi.x; o.y = acc[i][1] + bi.y;
        o.z = acc[i][2] + bi.z; o.w = acc[i][3] + bi.w;
        *reinterpret_cast<float4*>(
            Out + (((size_t)(b * NH + h) * LSEQ) + l) * DHD + tn * 4) = o;
    }
}

// ---------------------------------------------------------------------------
// K2: sampled sparsity measure + zero-init of headmask/VmeanRaw (replaces two
// memset dispatches; runs before their consumers topk/attn_partial).
// ---------------------------------------------------------------------------
__global__ __launch_bounds__(256) void score_kernel(
    const float* __restrict__ Qt, const float* __restrict__ Kt,
    const int* __restrict__ idxs, float* __restrict__ M,
    unsigned* __restrict__ headmask, float* __restrict__ VmeanRaw)
{
    const int flat = blockIdx.x;             // 16384 blocks
    if (flat < 32) headmask[flat * 256 + threadIdx.x] = 0u;
    else if (flat < 40) VmeanRaw[(flat - 32) * 256 + threadIdx.x] = 0.f;

    const int xcd  = flat & 7;
    const int slot = flat >> 3;              // 0..2047
    const int bh   = xcd * 4 + (slot >> 9);  // 4 bh per XCD
    const int w    = threadIdx.x >> 6;
    const int lane = threadIdx.x & 63;
    const int l    = (slot & 511) * 4 + w;

    __shared__ float qs[4][DHD];
    qs[w][lane] = Qt[((size_t)bh * LSEQ + l) * DHD + lane];  // wave-local RAW

    float acc = 0.f;
    if (lane < NSAMP) {
        const int ks = idxs[l * NSAMP + lane];
        const float4* kr = reinterpret_cast<const float4*>(
            Kt + ((size_t)bh * LSEQ + ks) * DHD);
#pragma unroll
        for (int j = 0; j < 16; ++j) {
            const float4 kv = kr[j];
            acc += qs[w][j * 4 + 0] * kv.x + qs[w][j * 4 + 1] * kv.y +
                   qs[w][j * 4 + 2] * kv.z + qs[w][j * 4 + 3] * kv.w;
        }
    }
    float vmax = (lane < NSAMP) ? acc : -FLT_MAX;
    float vsum = (lane < NSAMP) ? acc : 0.f;
#pragma unroll
    for (int off = 32; off; off >>= 1) {
        vmax = fmaxf(vmax, __shfl_xor(vmax, off));
        vsum += __shfl_xor(vsum, off);
    }
    if (lane == 0) M[(size_t)bh * LSEQ + l] = vmax - vsum * (1.0f / LSEQ);
}

// ---------------------------------------------------------------------------
// K3: stable top-40 per (b,h); candidates in registers.
// ---------------------------------------------------------------------------
__global__ __launch_bounds__(256) void topk_kernel(
    const float* __restrict__ M, int* __restrict__ topidx,
    unsigned* __restrict__ headmask, unsigned char* __restrict__ slot)
{
    const int bh = blockIdx.x;
    const int b = bh >> 3, h = bh & 7;
    const int w = threadIdx.x >> 6, lane = threadIdx.x & 63;
    const int base = threadIdx.x * 8;

    float e[8];
    {
        const float4 v0 = *reinterpret_cast<const float4*>(M + (size_t)bh * LSEQ + base);
        const float4 v1 = *reinterpret_cast<const float4*>(M + (size_t)bh * LSEQ + base + 4);
        e[0] = v0.x; e[1] = v0.y; e[2] = v0.z; e[3] = v0.w;
        e[4] = v1.x; e[5] = v1.y; e[6] = v1.z; e[7] = v1.w;
    }

    __shared__ float rv[4];
    __shared__ int   ri[4];
    __shared__ int   winner;

    for (int t = 0; t < NTOP; ++t) {
        float bv = e[0]; int br = 0;
#pragma unroll
        for (int r = 1; r < 8; ++r)
            if (e[r] > bv) { bv = e[r]; br = r; }    // strict >: smallest r on tie
        int bi = base + br;
#pragma unroll
        for (int off = 32; off; off >>= 1) {
            const float ov = __shfl_xor(bv, off);
            const int   oi = __shfl_xor(bi, off);
            if (ov > bv || (ov == bv && oi < bi)) { bv = ov; bi = oi; }
        }
        if (lane == 0) { rv[w] = bv; ri[w] = bi; }
        __syncthreads();
        if (threadIdx.x == 0) {
            float fv = rv[0]; int fi = ri[0];
#pragma unroll
            for (int k = 1; k < 4; ++k)
                if (rv[k] > fv || (rv[k] == fv && ri[k] < fi)) { fv = rv[k]; fi = ri[k]; }
            topidx[bh * NTOP + t] = fi;
            atomicOr(&headmask[b * LSEQ + fi], 1u << h);
            slot[bh * LSEQ + fi] = (unsigned char)t;
            winner = fi;
        }
        __syncthreads();
        const int fi = winner;
        if ((fi >> 3) == threadIdx.x) e[fi & 7] = -FLT_MAX;
    }
}

// ---------------------------------------------------------------------------
// K4: flash split-K attention partials + V column-sum accumulation (vmean
// folded in — V is already staged here; saves a separate 32 MB pass).
// ---------------------------------------------------------------------------
__global__ __launch_bounds__(256) void attn_partial(
    const float* __restrict__ Qt, const float* __restrict__ Kt,
    const float* __restrict__ Vt, const int* __restrict__ topidx,
    float* __restrict__ psums, float* __restrict__ pacc,
    float* __restrict__ VmeanRaw)
{
    const int bh = blockIdx.x;
    const int c  = blockIdx.y;
    const int kbase = c * TK;
    const int tid = threadIdx.x;

    __shared__ float Qs[NTOP][DHD];
    __shared__ float Ks[TK][68];
    __shared__ float Vs[TK][68];
    __shared__ float Sc[TK][52];

    for (int i = tid; i < NTOP * DHD; i += 256) {
        const int q = i >> 6, d = i & 63;
        const int row = topidx[bh * NTOP + q];
        Qs[q][d] = Qt[((size_t)bh * LSEQ + row) * DHD + d];
    }
    {
        const int r0 = tid >> 4, c4 = tid & 15;
#pragma unroll
        for (int rr = 0; rr < 4; ++rr) {
            const int r = r0 + rr * 16;
            const size_t g = ((size_t)bh * LSEQ + kbase + r) * DHD + c4 * 4;
            *reinterpret_cast<float4*>(&Ks[r][c4 * 4]) =
                *reinterpret_cast<const float4*>(Kt + g);
            *reinterpret_cast<float4*>(&Vs[r][c4 * 4]) =
                *reinterpret_cast<const float4*>(Vt + g);
        }
    }
    __syncthreads();

    // V column partial sums (vmean fold-in)
    {
        const int d = tid & 63, part = tid >> 6;
        float s = 0.f;
#pragma unroll
        for (int i = 0; i < 16; ++i) s += Vs[part * 16 + i][d];
        atomicAdd(&VmeanRaw[bh * DHD + d], s);
    }

    // scores: thread -> (kloc = tid&15, qg = tid>>4); Ks reads 2-way/broadcast
    {
        const int kloc = tid & 15, qg = tid >> 4;
#pragma unroll
        for (int qit = 0; qit < 3; ++qit) {
            const int q = qg + qit * 16;
            if (q < NTOP) {
#pragma unroll
                for (int kb = 0; kb < 4; ++kb) {
                    const int k = kloc + kb * 16;
                    float acc = 0.f;
#pragma unroll
                    for (int j = 0; j < 16; ++j) {
                        const float4 kv = *reinterpret_cast<const float4*>(&Ks[k][j * 4]);
                        const float4 qv = *reinterpret_cast<const float4*>(&Qs[q][j * 4]);
                        acc += qv.x * kv.x + qv.y * kv.y + qv.z * kv.z + qv.w * kv.w;
                    }
                    Sc[k][q] = acc * QK_SCALE;
                }
            }
        }
    }
    __syncthreads();

    // exp + per-chunk partial sums. exp w/o max-subtraction: scores O(+-8),
    // fp32 exp overflows only past 88 — mathematically identical result.
    {
        const int w = tid >> 6, lane = tid & 63;
#pragma unroll
        for (int j = 0; j < 10; ++j) {
            const int q = w * 10 + j;
            const float ee = __expf(Sc[lane][q]);
            float s = ee;
#pragma unroll
            for (int off = 32; off; off >>= 1) s += __shfl_xor(s, off);
            Sc[lane][q] = ee;
            if (lane == 0) psums[((size_t)bh * NCHUNK + c) * NTOP + q] = s;
        }
    }
    __syncthreads();

    // partial PV
    {
        const int d = tid & 63, g = tid >> 6;
        const int q0 = g * 12;
        const int nq = (g < 3) ? 12 : 4;
        float acc[12] = {};
        for (int k = 0; k < TK; ++k) {
            const float v = Vs[k][d];
            const float4 s0 = *reinterpret_cast<const float4*>(&Sc[k][q0]);
            acc[0] = fmaf(s0.x, v, acc[0]); acc[1] = fmaf(s0.y, v, acc[1]);
            acc[2] = fmaf(s0.z, v, acc[2]); acc[3] = fmaf(s0.w, v, acc[3]);
            if (g < 3) {
                const float4 s1 = *reinterpret_cast<const float4*>(&Sc[k][q0 + 4]);
                const float4 s2 = *reinterpret_cast<const float4*>(&Sc[k][q0 + 8]);
                acc[4] = fmaf(s1.x, v, acc[4]); acc[5]  = fmaf(s1.y, v, acc[5]);
                acc[6] = fmaf(s1.z, v, acc[6]); acc[7]  = fmaf(s1.w, v, acc[7]);
                acc[8] = fmaf(s2.x, v, acc[8]); acc[9]  = fmaf(s2.y, v, acc[9]);
                acc[10] = fmaf(s2.z, v, acc[10]); acc[11] = fmaf(s2.w, v, acc[11]);
            }
        }
#pragma unroll
        for (int j = 0; j < 12; ++j)
            if (j < nq)
                pacc[(((size_t)bh * NCHUNK + c) * NTOP + q0 + j) * DHD + d] = acc[j];
    }
}

// ---------------------------------------------------------------------------
// K5: combine partials -> delta = upd - Vmean; blocks with bh%8==0 also
// compute the per-batch mean output row (meanout fold-in).
// ---------------------------------------------------------------------------
__global__ __launch_bounds__(256) void attn_combine(
    const float* __restrict__ psums, const float* __restrict__ pacc,
    const float* __restrict__ VmeanRaw, const float* __restrict__ Wo,
    const float* __restrict__ bo, float* __restrict__ delta,
    float* __restrict__ meanout)
{
    const int bh = blockIdx.x;
    __shared__ float winv[NTOP];
    __shared__ float mc[DMODEL];
    if (threadIdx.x < NTOP) {
        float s = 0.f;
        for (int c = 0; c < NCHUNK; ++c)
            s += psums[((size_t)bh * NCHUNK + c) * NTOP + threadIdx.x];
        winv[threadIdx.x] = 1.0f / s;
    }
    __syncthreads();
    const int d = threadIdx.x & 63, g = threadIdx.x >> 6;
    const float vm = VmeanRaw[bh * DHD + d] * (1.0f / (float)LSEQ);
    for (int q = g; q < NTOP; q += 4) {
        float a = 0.f;
        for (int c = 0; c < NCHUNK; ++c)
            a += pacc[(((size_t)bh * NCHUNK + c) * NTOP + q) * DHD + d];
        delta[((size_t)bh * NTOP + q) * DHD + d] = a * winv[q] - vm;
    }

    if ((bh & 7) == 0) {               // block-uniform branch: barriers legal
        const int b = bh >> 3;
        for (int i = threadIdx.x; i < DMODEL; i += 256)
            mc[i] = VmeanRaw[b * DMODEL + i] * (1.0f / (float)LSEQ);
        __syncthreads();
        for (int n = threadIdx.x; n < DMODEL; n += 256) {
            float acc = bo[n];
            const float* wr = Wo + (size_t)n * DMODEL;
            for (int k = 0; k < DMODEL; ++k) acc = fmaf(mc[k], wr[k], acc);
            meanout[b * DMODEL + n] = acc;
        }
    }
}

// ---------------------------------------------------------------------------
// K6: final output rows; 128 threads, float4 path.
// ---------------------------------------------------------------------------
__global__ __launch_bounds__(128) void out_kernel(
    const float* __restrict__ meanout, const unsigned* __restrict__ headmask,
    const unsigned char* __restrict__ slot, const float* __restrict__ delta,
    const float* __restrict__ Wo, float* __restrict__ out)
{
    const int rowg = blockIdx.x;
    const int b = rowg >> 11, lloc = rowg & (LSEQ - 1);
    const unsigned mask = headmask[rowg];

    __shared__ float dl[NH][DHD];
    if (threadIdx.x < DHD) {
        for (int h = 0; h < NH; ++h) {
            if ((mask >> h) & 1) {
                const int bh = b * NH + h;
                const int u = slot[bh * LSEQ + lloc];
                dl[h][threadIdx.x] = delta[((size_t)bh * NTOP + u) * DHD + threadIdx.x];
            }
        }
    }
    __syncthreads();

    const int n4 = threadIdx.x;           // 0..127 float4-chunks of 512
    float4 val = *reinterpret_cast<const float4*>(meanout + b * DMODEL + n4 * 4);
    unsigned mm = mask;
    while (mm) {
        const int h = __ffs(mm) - 1;
        mm &= mm - 1;
#pragma unroll
        for (int c = 0; c < 4; ++c) {
            const int n = n4 * 4 + c;
            const float4* wr4 = reinterpret_cast<const float4*>(
                Wo + (size_t)n * DMODEL + h * DHD);
            float a = 0.f;
#pragma unroll
            for (int dd = 0; dd < 16; ++dd) {
                const float4 wv = wr4[dd];
                a += dl[h][dd * 4 + 0] * wv.x + dl[h][dd * 4 + 1] * wv.y +
                     dl[h][dd * 4 + 2] * wv.z + dl[h][dd * 4 + 3] * wv.w;
            }
            (&val.x)[c] += a;
        }
    }
    *reinterpret_cast<float4*>(out + (size_t)rowg * DMODEL + n4 * 4) = val;
}

// ---------------------------------------------------------------------------
extern "C" void kernel_launch(void* const* d_in, const int* in_sizes, int n_in,
                              void* d_out, int out_size, void* d_ws, size_t ws_size,
                              hipStream_t stream)
{
    (void)in_sizes; (void)n_in; (void)out_size; (void)ws_size;
    const float* x     = (const float*)d_in[0];
    const float* ctxin = (const float*)d_in[1];
    const float* Wq    = (const float*)d_in[2];
    const float* bq    = (const float*)d_in[3];
    const float* Wk    = (const float*)d_in[4];
    const float* bk    = (const float*)d_in[5];
    const float* Wv    = (const float*)d_in[6];
    const float* bv    = (const float*)d_in[7];
    const float* Wo    = (const float*)d_in[8];
    const float* bo    = (const float*)d_in[9];
    const int*   idxs  = (const int*)d_in[10];
    float* out = (float*)d_out;

    char* ws = (char*)d_ws;
    size_t off = 0;
    auto alloc = [&](size_t bytes) -> void* {
        void* p = ws + off;
        off += (bytes + 255) & ~(size_t)255;
        return p;
    };

    const size_t qkv_bytes = (size_t)BATCH * NH * LSEQ * DHD * sizeof(float);
    float*         Qt       = (float*)alloc(qkv_bytes);
    float*         Kt       = (float*)alloc(qkv_bytes);
    float*         Vt       = (float*)alloc(qkv_bytes);
    float*         Mbuf     = (float*)alloc((size_t)BATCH * NH * LSEQ * sizeof(float));
    float*         VmeanRaw = (float*)alloc((size_t)BATCH * NH * DHD * sizeof(float));
    float*         meanout  = (float*)alloc((size_t)BATCH * DMODEL * sizeof(float));
    float*         delta    = (float*)alloc((size_t)BATCH * NH * NTOP * DHD * sizeof(float));
    int*           topidx   = (int*)alloc((size_t)BATCH * NH * NTOP * sizeof(int));
    unsigned*      headmask = (unsigned*)alloc((size_t)BATCH * LSEQ * sizeof(unsigned));
    unsigned char* slot     = (unsigned char*)alloc((size_t)BATCH * NH * LSEQ);
    float*         psums    = (float*)alloc((size_t)BATCH * NH * NCHUNK * NTOP * sizeof(float));
    float*         pacc     = (float*)alloc((size_t)BATCH * NH * NCHUNK * NTOP * DHD * sizeof(float));

    qkv_gemm_f32<<<dim3(8192 / 128, DMODEL / 64, 3), 256, 0, stream>>>(
        x, ctxin, Wq, bq, Wk, bk, Wv, bv, Qt, Kt, Vt);

    score_kernel<<<(BATCH * NH * LSEQ) / 4, 256, 0, stream>>>(
        Qt, Kt, idxs, Mbuf, headmask, VmeanRaw);

    topk_kernel<<<BATCH * NH, 256, 0, stream>>>(Mbuf, topidx, headmask, slot);

    attn_partial<<<dim3(BATCH * NH, NCHUNK), 256, 0, stream>>>(
        Qt, Kt, Vt, topidx, psums, pacc, VmeanRaw);

    attn_combine<<<BATCH * NH, 256, 0, stream>>>(
        psums, pacc, VmeanRaw, Wo, bo, delta, meanout);

    out_kernel<<<BATCH * LSEQ, 128, 0, stream>>>(
        meanout, headmask, slot, delta, Wo, out);
}

// Round 7
// 414.486 us; speedup vs baseline: 1.3209x; 1.1067x over previous
//
#include <hip/hip_runtime.h>
#include <float.h>

#define BATCH 4
#define LSEQ  2048
#define DMODEL 512
#define NH    8
#define DHD   64
#define NSAMP 40
#define NTOP  40
#define NCHUNK 32
#define TK    64
#define QK_SCALE 0.125f

typedef unsigned short u16;
typedef __attribute__((ext_vector_type(8))) short short8b;  // 8 bf16 = 16 B
typedef __attribute__((ext_vector_type(4))) float f32x4;

// RTNE float->bf16 on raw bits (no header-type dependence; inputs finite).
static __device__ __forceinline__ u16 f2bf(float x) {
    unsigned u = __float_as_uint(x);
    u += 0x7FFFu + ((u >> 16) & 1u);
    return (u16)(u >> 16);
}
static __device__ __forceinline__ float bf2f(u16 s) {
    return __uint_as_float((unsigned)s << 16);
}

// ---------------------------------------------------------------------------
// K0: 3-way bf16 split: x = s1 + s2 + s3 + O(2^-27 |x|).
// ---------------------------------------------------------------------------
__global__ __launch_bounds__(256) void split3_kernel(
    const float* __restrict__ src, u16* __restrict__ p1,
    u16* __restrict__ p2, u16* __restrict__ p3, int n4)
{
    for (int i = blockIdx.x * 256 + threadIdx.x; i < n4; i += gridDim.x * 256) {
        const float4 v = reinterpret_cast<const float4*>(src)[i];
        const float in[4] = {v.x, v.y, v.z, v.w};
        ushort4 o1, o2, o3;
        u16 b1[4], b2[4], b3[4];
#pragma unroll
        for (int c = 0; c < 4; ++c) {
            const float x = in[c];
            b1[c] = f2bf(x);
            const float r1 = x - bf2f(b1[c]);
            b2[c] = f2bf(r1);
            const float r2 = r1 - bf2f(b2[c]);
            b3[c] = f2bf(r2);
        }
        o1.x = b1[0]; o1.y = b1[1]; o1.z = b1[2]; o1.w = b1[3];
        o2.x = b2[0]; o2.y = b2[1]; o2.z = b2[2]; o2.w = b2[3];
        o3.x = b3[0]; o3.y = b3[1]; o3.z = b3[2]; o3.w = b3[3];
        reinterpret_cast<ushort4*>(p1)[i] = o1;
        reinterpret_cast<ushort4*>(p2)[i] = o2;
        reinterpret_cast<ushort4*>(p3)[i] = o3;
    }
}

// ---------------------------------------------------------------------------
// K1: QKV GEMM on MFMA via bf16x3 split (6 products: 11,12,21,13,31,22 —
// fp32-GEMM-level accuracy; M-selection error ~1e-6).
// C = A @ W^T + b. Tile 128m x 64n, BK=32, 4 waves (each 32m x 64n).
// mfma_f32_16x16x32_bf16: A-frag = A[m=lane&15][k=(lane>>4)*8+i] (16B row
// chunk), B-frag = W[n=lane&15][k...], C col=lane&15, row=(lane>>4)*4+r.
// LDS rows padded to 40 u16 (80 B): bank spread gcd(20,32)=4 -> ~2-way free.
// XCD-chunked decode: each XCD owns 8 m-panels x all n -> panels+W fetched
// once per XCD (HBM ~80 MB total).
// ---------------------------------------------------------------------------
__global__ __launch_bounds__(256) void qkv_gemm_mfma(
    const u16* __restrict__ xs1, const u16* __restrict__ xs2, const u16* __restrict__ xs3,
    const u16* __restrict__ cs1, const u16* __restrict__ cs2, const u16* __restrict__ cs3,
    const u16* __restrict__ wq1, const u16* __restrict__ wq2, const u16* __restrict__ wq3,
    const u16* __restrict__ wk1, const u16* __restrict__ wk2, const u16* __restrict__ wk3,
    const u16* __restrict__ wv1, const u16* __restrict__ wv2, const u16* __restrict__ wv3,
    const float* __restrict__ bq, const float* __restrict__ bk, const float* __restrict__ bv,
    float* __restrict__ Qt, float* __restrict__ Kt, float* __restrict__ Vt)
{
    const int z = blockIdx.y;
    const int i = blockIdx.x;            // 0..511, x fastest -> i&7 = XCD
    const int xcd = i & 7;
    const int loc = i >> 3;              // 0..63
    const int m0 = (xcd * 8 + (loc & 7)) * 128;
    const int n0 = (loc >> 3) * 64;

    const u16* Ap[3];
    const u16* Wp[3];
    if (z == 0) { Ap[0] = xs1; Ap[1] = xs2; Ap[2] = xs3; }
    else        { Ap[0] = cs1; Ap[1] = cs2; Ap[2] = cs3; }
    if (z == 0)      { Wp[0] = wq1; Wp[1] = wq2; Wp[2] = wq3; }
    else if (z == 1) { Wp[0] = wk1; Wp[1] = wk2; Wp[2] = wk3; }
    else             { Wp[0] = wv1; Wp[1] = wv2; Wp[2] = wv3; }
    const float* bias = (z == 0) ? bq : (z == 1 ? bk : bv);
    float*       Out  = (z == 0) ? Qt : (z == 1 ? Kt : Vt);

    __shared__ u16 As[3][128][40];   // 30720 B (cols 32..39 pad)
    __shared__ u16 Ws[3][64][40];    // 15360 B

    const int tid  = threadIdx.x;
    const int w    = tid >> 6;
    const int lane = tid & 63;
    const int lr   = lane & 15;      // frag row (m or n)
    const int lg   = lane >> 4;      // k-chunk 0..3
    const int w32  = w * 32;

    f32x4 acc[2][4];
#pragma unroll
    for (int mf = 0; mf < 2; ++mf)
#pragma unroll
        for (int nf = 0; nf < 4; ++nf)
#pragma unroll
            for (int r = 0; r < 4; ++r) acc[mf][nf][r] = 0.f;

    const int srow = tid >> 2;       // 0..63
    const int skb  = tid & 3;

    for (int k0 = 0; k0 < DMODEL; k0 += 32) {
        // stage: A = 6 passes (plane p>>1, row half p&1), W = 3 passes
#pragma unroll
        for (int p = 0; p < 6; ++p) {
            const int pl = p >> 1;
            const int row = (p & 1) * 64 + srow;
            *reinterpret_cast<short8b*>(&As[pl][row][skb * 8]) =
                *reinterpret_cast<const short8b*>(
                    Ap[pl] + (size_t)(m0 + row) * DMODEL + k0 + skb * 8);
        }
#pragma unroll
        for (int p = 0; p < 3; ++p) {
            *reinterpret_cast<short8b*>(&Ws[p][srow][skb * 8]) =
                *reinterpret_cast<const short8b*>(
                    Wp[p] + (size_t)(n0 + srow) * DMODEL + k0 + skb * 8);
        }
        __syncthreads();

        short8b af[2][3];
#pragma unroll
        for (int mf = 0; mf < 2; ++mf) {
            const int row = w32 + mf * 16 + lr;
#pragma unroll
            for (int p = 0; p < 3; ++p)
                af[mf][p] = *reinterpret_cast<const short8b*>(&As[p][row][lg * 8]);
        }
#pragma unroll
        for (int nf = 0; nf < 4; ++nf) {
            const int row = nf * 16 + lr;
            const short8b b1 = *reinterpret_cast<const short8b*>(&Ws[0][row][lg * 8]);
            const short8b b2 = *reinterpret_cast<const short8b*>(&Ws[1][row][lg * 8]);
            const short8b b3 = *reinterpret_cast<const short8b*>(&Ws[2][row][lg * 8]);
#pragma unroll
            for (int mf = 0; mf < 2; ++mf) {
                acc[mf][nf] = __builtin_amdgcn_mfma_f32_16x16x32_bf16(af[mf][0], b1, acc[mf][nf], 0, 0, 0);
                acc[mf][nf] = __builtin_amdgcn_mfma_f32_16x16x32_bf16(af[mf][1], b1, acc[mf][nf], 0, 0, 0);
                acc[mf][nf] = __builtin_amdgcn_mfma_f32_16x16x32_bf16(af[mf][0], b2, acc[mf][nf], 0, 0, 0);
                acc[mf][nf] = __builtin_amdgcn_mfma_f32_16x16x32_bf16(af[mf][2], b1, acc[mf][nf], 0, 0, 0);
                acc[mf][nf] = __builtin_amdgcn_mfma_f32_16x16x32_bf16(af[mf][0], b3, acc[mf][nf], 0, 0, 0);
                acc[mf][nf] = __builtin_amdgcn_mfma_f32_16x16x32_bf16(af[mf][1], b2, acc[mf][nf], 0, 0, 0);
            }
        }
        __syncthreads();
    }

    // epilogue: C col = lane&15 (n), row = lg*4 + r (m-local)
#pragma unroll
    for (int nf = 0; nf < 4; ++nf) {
        const int n = n0 + nf * 16 + lr;
        const int h = n >> 6, d = n & 63;
        const float bv_ = bias[n];
#pragma unroll
        for (int mf = 0; mf < 2; ++mf) {
#pragma unroll
            for (int r = 0; r < 4; ++r) {
                const int m = m0 + w32 + mf * 16 + lg * 4 + r;
                const int b = m >> 11, l = m & (LSEQ - 1);
                Out[((size_t)(b * NH + h) * LSEQ + l) * DHD + d] = acc[mf][nf][r] + bv_;
            }
        }
    }
}

// ---------------------------------------------------------------------------
// K2: sampled sparsity measure + zero-init of headmask/VmeanRaw.
// ---------------------------------------------------------------------------
__global__ __launch_bounds__(256) void score_kernel(
    const float* __restrict__ Qt, const float* __restrict__ Kt,
    const int* __restrict__ idxs, float* __restrict__ M,
    unsigned* __restrict__ headmask, float* __restrict__ VmeanRaw)
{
    const int flat = blockIdx.x;
    if (flat < 32) headmask[flat * 256 + threadIdx.x] = 0u;
    else if (flat < 40) VmeanRaw[(flat - 32) * 256 + threadIdx.x] = 0.f;

    const int xcd  = flat & 7;
    const int slot = flat >> 3;
    const int bh   = xcd * 4 + (slot >> 9);
    const int w    = threadIdx.x >> 6;
    const int lane = threadIdx.x & 63;
    const int l    = (slot & 511) * 4 + w;

    __shared__ float qs[4][DHD];
    qs[w][lane] = Qt[((size_t)bh * LSEQ + l) * DHD + lane];

    float acc = 0.f;
    if (lane < NSAMP) {
        const int ks = idxs[l * NSAMP + lane];
        const float4* kr = reinterpret_cast<const float4*>(
            Kt + ((size_t)bh * LSEQ + ks) * DHD);
#pragma unroll
        for (int j = 0; j < 16; ++j) {
            const float4 kv = kr[j];
            acc += qs[w][j * 4 + 0] * kv.x + qs[w][j * 4 + 1] * kv.y +
                   qs[w][j * 4 + 2] * kv.z + qs[w][j * 4 + 3] * kv.w;
        }
    }
    float vmax = (lane < NSAMP) ? acc : -FLT_MAX;
    float vsum = (lane < NSAMP) ? acc : 0.f;
#pragma unroll
    for (int off = 32; off; off >>= 1) {
        vmax = fmaxf(vmax, __shfl_xor(vmax, off));
        vsum += __shfl_xor(vsum, off);
    }
    if (lane == 0) M[(size_t)bh * LSEQ + l] = vmax - vsum * (1.0f / LSEQ);
}

// ---------------------------------------------------------------------------
// K3: stable top-40 per (b,h); candidates in registers.
// ---------------------------------------------------------------------------
__global__ __launch_bounds__(256) void topk_kernel(
    const float* __restrict__ M, int* __restrict__ topidx,
    unsigned* __restrict__ headmask, unsigned char* __restrict__ slot)
{
    const int bh = blockIdx.x;
    const int b = bh >> 3, h = bh & 7;
    const int w = threadIdx.x >> 6, lane = threadIdx.x & 63;
    const int base = threadIdx.x * 8;

    float e[8];
    {
        const float4 v0 = *reinterpret_cast<const float4*>(M + (size_t)bh * LSEQ + base);
        const float4 v1 = *reinterpret_cast<const float4*>(M + (size_t)bh * LSEQ + base + 4);
        e[0] = v0.x; e[1] = v0.y; e[2] = v0.z; e[3] = v0.w;
        e[4] = v1.x; e[5] = v1.y; e[6] = v1.z; e[7] = v1.w;
    }

    __shared__ float rv[4];
    __shared__ int   ri[4];
    __shared__ int   winner;

    for (int t = 0; t < NTOP; ++t) {
        float bv = e[0]; int br = 0;
#pragma unroll
        for (int r = 1; r < 8; ++r)
            if (e[r] > bv) { bv = e[r]; br = r; }
        int bi = base + br;
#pragma unroll
        for (int off = 32; off; off >>= 1) {
            const float ov = __shfl_xor(bv, off);
            const int   oi = __shfl_xor(bi, off);
            if (ov > bv || (ov == bv && oi < bi)) { bv = ov; bi = oi; }
        }
        if (lane == 0) { rv[w] = bv; ri[w] = bi; }
        __syncthreads();
        if (threadIdx.x == 0) {
            float fv = rv[0]; int fi = ri[0];
#pragma unroll
            for (int k = 1; k < 4; ++k)
                if (rv[k] > fv || (rv[k] == fv && ri[k] < fi)) { fv = rv[k]; fi = ri[k]; }
            topidx[bh * NTOP + t] = fi;
            atomicOr(&headmask[b * LSEQ + fi], 1u << h);
            slot[bh * LSEQ + fi] = (unsigned char)t;
            winner = fi;
        }
        __syncthreads();
        const int fi = winner;
        if ((fi >> 3) == threadIdx.x) e[fi & 7] = -FLT_MAX;
    }
}

// ---------------------------------------------------------------------------
// K4: flash split-K attention partials + V column-sum accumulation.
// ---------------------------------------------------------------------------
__global__ __launch_bounds__(256) void attn_partial(
    const float* __restrict__ Qt, const float* __restrict__ Kt,
    const float* __restrict__ Vt, const int* __restrict__ topidx,
    float* __restrict__ psums, float* __restrict__ pacc,
    float* __restrict__ VmeanRaw)
{
    const int bh = blockIdx.x;
    const int c  = blockIdx.y;
    const int kbase = c * TK;
    const int tid = threadIdx.x;

    __shared__ float Qs[NTOP][DHD];
    __shared__ float Ks[TK][68];
    __shared__ float Vs[TK][68];
    __shared__ float Sc[TK][52];

    for (int i = tid; i < NTOP * DHD; i += 256) {
        const int q = i >> 6, d = i & 63;
        const int row = topidx[bh * NTOP + q];
        Qs[q][d] = Qt[((size_t)bh * LSEQ + row) * DHD + d];
    }
    {
        const int r0 = tid >> 4, c4 = tid & 15;
#pragma unroll
        for (int rr = 0; rr < 4; ++rr) {
            const int r = r0 + rr * 16;
            const size_t g = ((size_t)bh * LSEQ + kbase + r) * DHD + c4 * 4;
            *reinterpret_cast<float4*>(&Ks[r][c4 * 4]) =
                *reinterpret_cast<const float4*>(Kt + g);
            *reinterpret_cast<float4*>(&Vs[r][c4 * 4]) =
                *reinterpret_cast<const float4*>(Vt + g);
        }
    }
    __syncthreads();

    {
        const int d = tid & 63, part = tid >> 6;
        float s = 0.f;
#pragma unroll
        for (int i = 0; i < 16; ++i) s += Vs[part * 16 + i][d];
        atomicAdd(&VmeanRaw[bh * DHD + d], s);
    }

    {
        const int kloc = tid & 15, qg = tid >> 4;
#pragma unroll
        for (int qit = 0; qit < 3; ++qit) {
            const int q = qg + qit * 16;
            if (q < NTOP) {
#pragma unroll
                for (int kb = 0; kb < 4; ++kb) {
                    const int k = kloc + kb * 16;
                    float acc = 0.f;
#pragma unroll
                    for (int j = 0; j < 16; ++j) {
                        const float4 kv = *reinterpret_cast<const float4*>(&Ks[k][j * 4]);
                        const float4 qv = *reinterpret_cast<const float4*>(&Qs[q][j * 4]);
                        acc += qv.x * kv.x + qv.y * kv.y + qv.z * kv.z + qv.w * kv.w;
                    }
                    Sc[k][q] = acc * QK_SCALE;
                }
            }
        }
    }
    __syncthreads();

    {
        const int w = tid >> 6, lane = tid & 63;
#pragma unroll
        for (int j = 0; j < 10; ++j) {
            const int q = w * 10 + j;
            const float ee = __expf(Sc[lane][q]);
            float s = ee;
#pragma unroll
            for (int off = 32; off; off >>= 1) s += __shfl_xor(s, off);
            Sc[lane][q] = ee;
            if (lane == 0) psums[((size_t)bh * NCHUNK + c) * NTOP + q] = s;
        }
    }
    __syncthreads();

    {
        const int d = tid & 63, g = tid >> 6;
        const int q0 = g * 12;
        const int nq = (g < 3) ? 12 : 4;
        float acc[12] = {};
        for (int k = 0; k < TK; ++k) {
            const float v = Vs[k][d];
            const float4 s0 = *reinterpret_cast<const float4*>(&Sc[k][q0]);
            acc[0] = fmaf(s0.x, v, acc[0]); acc[1] = fmaf(s0.y, v, acc[1]);
            acc[2] = fmaf(s0.z, v, acc[2]); acc[3] = fmaf(s0.w, v, acc[3]);
            if (g < 3) {
                const float4 s1 = *reinterpret_cast<const float4*>(&Sc[k][q0 + 4]);
                const float4 s2 = *reinterpret_cast<const float4*>(&Sc[k][q0 + 8]);
                acc[4] = fmaf(s1.x, v, acc[4]); acc[5]  = fmaf(s1.y, v, acc[5]);
                acc[6] = fmaf(s1.z, v, acc[6]); acc[7]  = fmaf(s1.w, v, acc[7]);
                acc[8] = fmaf(s2.x, v, acc[8]); acc[9]  = fmaf(s2.y, v, acc[9]);
                acc[10] = fmaf(s2.z, v, acc[10]); acc[11] = fmaf(s2.w, v, acc[11]);
            }
        }
#pragma unroll
        for (int j = 0; j < 12; ++j)
            if (j < nq)
                pacc[(((size_t)bh * NCHUNK + c) * NTOP + q0 + j) * DHD + d] = acc[j];
    }
}

// ---------------------------------------------------------------------------
// K5: combine partials -> delta; bh%8==0 blocks also compute meanout.
// ---------------------------------------------------------------------------
__global__ __launch_bounds__(256) void attn_combine(
    const float* __restrict__ psums, const float* __restrict__ pacc,
    const float* __restrict__ VmeanRaw, const float* __restrict__ Wo,
    const float* __restrict__ bo, float* __restrict__ delta,
    float* __restrict__ meanout)
{
    const int bh = blockIdx.x;
    __shared__ float winv[NTOP];
    __shared__ float mc[DMODEL];
    if (threadIdx.x < NTOP) {
        float s = 0.f;
        for (int c = 0; c < NCHUNK; ++c)
            s += psums[((size_t)bh * NCHUNK + c) * NTOP + threadIdx.x];
        winv[threadIdx.x] = 1.0f / s;
    }
    __syncthreads();
    const int d = threadIdx.x & 63, g = threadIdx.x >> 6;
    const float vm = VmeanRaw[bh * DHD + d] * (1.0f / (float)LSEQ);
    for (int q = g; q < NTOP; q += 4) {
        float a = 0.f;
        for (int c = 0; c < NCHUNK; ++c)
            a += pacc[(((size_t)bh * NCHUNK + c) * NTOP + q) * DHD + d];
        delta[((size_t)bh * NTOP + q) * DHD + d] = a * winv[q] - vm;
    }

    if ((bh & 7) == 0) {
        const int b = bh >> 3;
        for (int i = threadIdx.x; i < DMODEL; i += 256)
            mc[i] = VmeanRaw[b * DMODEL + i] * (1.0f / (float)LSEQ);
        __syncthreads();
        for (int n = threadIdx.x; n < DMODEL; n += 256) {
            float acc = bo[n];
            const float* wr = Wo + (size_t)n * DMODEL;
            for (int k = 0; k < DMODEL; ++k) acc = fmaf(mc[k], wr[k], acc);
            meanout[b * DMODEL + n] = acc;
        }
    }
}

// ---------------------------------------------------------------------------
// K6: final output rows; 128 threads, float4 path.
// ---------------------------------------------------------------------------
__global__ __launch_bounds__(128) void out_kernel(
    const float* __restrict__ meanout, const unsigned* __restrict__ headmask,
    const unsigned char* __restrict__ slot, const float* __restrict__ delta,
    const float* __restrict__ Wo, float* __restrict__ out)
{
    const int rowg = blockIdx.x;
    const int b = rowg >> 11, lloc = rowg & (LSEQ - 1);
    const unsigned mask = headmask[rowg];

    __shared__ float dl[NH][DHD];
    if (threadIdx.x < DHD) {
        for (int h = 0; h < NH; ++h) {
            if ((mask >> h) & 1) {
                const int bh = b * NH + h;
                const int u = slot[bh * LSEQ + lloc];
                dl[h][threadIdx.x] = delta[((size_t)bh * NTOP + u) * DHD + threadIdx.x];
            }
        }
    }
    __syncthreads();

    const int n4 = threadIdx.x;
    float4 val = *reinterpret_cast<const float4*>(meanout + b * DMODEL + n4 * 4);
    unsigned mm = mask;
    while (mm) {
        const int h = __ffs(mm) - 1;
        mm &= mm - 1;
#pragma unroll
        for (int c = 0; c < 4; ++c) {
            const int n = n4 * 4 + c;
            const float4* wr4 = reinterpret_cast<const float4*>(
                Wo + (size_t)n * DMODEL + h * DHD);
            float a = 0.f;
#pragma unroll
            for (int dd = 0; dd < 16; ++dd) {
                const float4 wv = wr4[dd];
                a += dl[h][dd * 4 + 0] * wv.x + dl[h][dd * 4 + 1] * wv.y +
                     dl[h][dd * 4 + 2] * wv.z + dl[h][dd * 4 + 3] * wv.w;
            }
            (&val.x)[c] += a;
        }
    }
    *reinterpret_cast<float4*>(out + (size_t)rowg * DMODEL + n4 * 4) = val;
}

// ---------------------------------------------------------------------------
extern "C" void kernel_launch(void* const* d_in, const int* in_sizes, int n_in,
                              void* d_out, int out_size, void* d_ws, size_t ws_size,
                              hipStream_t stream)
{
    (void)in_sizes; (void)n_in; (void)out_size; (void)ws_size;
    const float* x     = (const float*)d_in[0];
    const float* ctxin = (const float*)d_in[1];
    const float* Wq    = (const float*)d_in[2];
    const float* bq    = (const float*)d_in[3];
    const float* Wk    = (const float*)d_in[4];
    const float* bk    = (const float*)d_in[5];
    const float* Wv    = (const float*)d_in[6];
    const float* bv    = (const float*)d_in[7];
    const float* Wo    = (const float*)d_in[8];
    const float* bo    = (const float*)d_in[9];
    const int*   idxs  = (const int*)d_in[10];
    float* out = (float*)d_out;

    char* ws = (char*)d_ws;
    size_t off = 0;
    auto alloc = [&](size_t bytes) -> void* {
        void* p = ws + off;
        off += (bytes + 255) & ~(size_t)255;
        return p;
    };

    const size_t qkv_bytes = (size_t)BATCH * NH * LSEQ * DHD * sizeof(float);
    const size_t SEQD = (size_t)BATCH * LSEQ * DMODEL;      // 4.19M elems
    const size_t WN   = (size_t)DMODEL * DMODEL;            // 0.26M elems

    float*         Qt       = (float*)alloc(qkv_bytes);
    float*         Kt       = (float*)alloc(qkv_bytes);
    float*         Vt       = (float*)alloc(qkv_bytes);
    float*         Mbuf     = (float*)alloc((size_t)BATCH * NH * LSEQ * sizeof(float));
    float*         VmeanRaw = (float*)alloc((size_t)BATCH * NH * DHD * sizeof(float));
    float*         meanout  = (float*)alloc((size_t)BATCH * DMODEL * sizeof(float));
    float*         delta    = (float*)alloc((size_t)BATCH * NH * NTOP * DHD * sizeof(float));
    int*           topidx   = (int*)alloc((size_t)BATCH * NH * NTOP * sizeof(int));
    unsigned*      headmask = (unsigned*)alloc((size_t)BATCH * LSEQ * sizeof(unsigned));
    unsigned char* slot     = (unsigned char*)alloc((size_t)BATCH * NH * LSEQ);
    float*         psums    = (float*)alloc((size_t)BATCH * NH * NCHUNK * NTOP * sizeof(float));
    u16*           xs1      = (u16*)alloc(SEQD * 2);
    u16*           xs2      = (u16*)alloc(SEQD * 2);
    u16*           xs3      = (u16*)alloc(SEQD * 2);
    u16*           cs1      = (u16*)alloc(SEQD * 2);
    u16*           cs2      = (u16*)alloc(SEQD * 2);
    u16*           cs3      = (u16*)alloc(SEQD * 2);
    u16*           wq1      = (u16*)alloc(WN * 2);
    u16*           wq2      = (u16*)alloc(WN * 2);
    u16*           wq3      = (u16*)alloc(WN * 2);
    u16*           wk1      = (u16*)alloc(WN * 2);
    u16*           wk2      = (u16*)alloc(WN * 2);
    u16*           wk3      = (u16*)alloc(WN * 2);
    u16*           wv1      = (u16*)alloc(WN * 2);
    u16*           wv2      = (u16*)alloc(WN * 2);
    u16*           wv3      = (u16*)alloc(WN * 2);
    // pacc (10.5 MB) aliases the x-split planes: splits are dead once
    // qkv_gemm_mfma completes; attn_partial runs strictly after it.
    float*         pacc     = (float*)xs1;

    split3_kernel<<<1024, 256, 0, stream>>>(x,     xs1, xs2, xs3, (int)(SEQD / 4));
    split3_kernel<<<1024, 256, 0, stream>>>(ctxin, cs1, cs2, cs3, (int)(SEQD / 4));
    split3_kernel<<<256, 256, 0, stream>>>(Wq, wq1, wq2, wq3, (int)(WN / 4));
    split3_kernel<<<256, 256, 0, stream>>>(Wk, wk1, wk2, wk3, (int)(WN / 4));
    split3_kernel<<<256, 256, 0, stream>>>(Wv, wv1, wv2, wv3, (int)(WN / 4));

    qkv_gemm_mfma<<<dim3(512, 3), 256, 0, stream>>>(
        xs1, xs2, xs3, cs1, cs2, cs3,
        wq1, wq2, wq3, wk1, wk2, wk3, wv1, wv2, wv3,
        bq, bk, bv, Qt, Kt, Vt);

    score_kernel<<<(BATCH * NH * LSEQ) / 4, 256, 0, stream>>>(
        Qt, Kt, idxs, Mbuf, headmask, VmeanRaw);

    topk_kernel<<<BATCH * NH, 256, 0, stream>>>(Mbuf, topidx, headmask, slot);

    attn_partial<<<dim3(BATCH * NH, NCHUNK), 256, 0, stream>>>(
        Qt, Kt, Vt, topidx, psums, pacc, VmeanRaw);

    attn_combine<<<BATCH * NH, 256, 0, stream>>>(
        psums, pacc, VmeanRaw, Wo, bo, delta, meanout);

    out_kernel<<<BATCH * LSEQ, 128, 0, stream>>>(
        meanout, headmask, slot, delta, Wo, out);
}

// Round 8
// 336.458 us; speedup vs baseline: 1.6272x; 1.2319x over previous
//
#include <hip/hip_runtime.h>
#include <float.h>

#define BATCH 4
#define LSEQ  2048
#define DMODEL 512
#define NH    8
#define DHD   64
#define NSAMP 40
#define NTOP  40
#define NCHUNK 32
#define TK    64
#define QK_SCALE 0.125f

typedef unsigned short u16;
typedef __attribute__((ext_vector_type(8))) short short8b;  // 8 bf16 = 16 B
typedef __attribute__((ext_vector_type(4))) float f32x4;

// RTNE float->bf16 on raw bits (inputs finite).
static __device__ __forceinline__ u16 f2bf(float x) {
    unsigned u = __float_as_uint(x);
    u += 0x7FFFu + ((u >> 16) & 1u);
    return (u16)(u >> 16);
}
static __device__ __forceinline__ float bf2f(u16 s) {
    return __uint_as_float((unsigned)s << 16);
}
// 8-float -> 3 bf16 planes (x = p1 + p2 + p3 + O(2^-27 |x|))
static __device__ __forceinline__ void cvt8(
    const float4 a, const float4 b, short8b& o1, short8b& o2, short8b& o3)
{
    const float in[8] = {a.x, a.y, a.z, a.w, b.x, b.y, b.z, b.w};
#pragma unroll
    for (int c = 0; c < 8; ++c) {
        const float x = in[c];
        const u16 v1 = f2bf(x);
        const float r1 = x - bf2f(v1);
        const u16 v2 = f2bf(r1);
        const float r2 = r1 - bf2f(v2);
        const u16 v3 = f2bf(r2);
        o1[c] = (short)v1; o2[c] = (short)v2; o3[c] = (short)v3;
    }
}

// ---------------------------------------------------------------------------
// K1: QKV GEMM on MFMA via in-kernel bf16x3 split (6 products: 11,12,21,
// 13,31,22 — fp32-GEMM-level accuracy). C = A @ W^T + b.
// Tile 128m x 64n, BK=32, 4 waves. Stages fp32 A/W, converts to 3 bf16
// planes in the LDS-write phase (no separate split kernels). T14 async-
// stage: next tile's global loads issue before the MFMA phase.
// LDS rows padded to 40 u16 (80 B): 2-way banks (free). XCD-chunked decode.
// ---------------------------------------------------------------------------
__global__ __launch_bounds__(256) void qkv_gemm_mfma(
    const float* __restrict__ x, const float* __restrict__ ctxin,
    const float* __restrict__ Wq, const float* __restrict__ Wk,
    const float* __restrict__ Wv,
    const float* __restrict__ bq, const float* __restrict__ bk,
    const float* __restrict__ bv,
    float* __restrict__ Qt, float* __restrict__ Kt, float* __restrict__ Vt)
{
    const int z = blockIdx.y;
    const int i = blockIdx.x;            // 0..511
    const int xcd = i & 7;
    const int loc = i >> 3;              // 0..63
    const int m0 = (xcd * 8 + (loc & 7)) * 128;
    const int n0 = (loc >> 3) * 64;

    const float* __restrict__ A    = (z == 0) ? x  : ctxin;
    const float* __restrict__ W    = (z == 0) ? Wq : (z == 1 ? Wk : Wv);
    const float* __restrict__ bias = (z == 0) ? bq : (z == 1 ? bk : bv);
    float*       __restrict__ Out  = (z == 0) ? Qt : (z == 1 ? Kt : Vt);

    __shared__ u16 As[3][128][40];   // 30720 B
    __shared__ u16 Ws[3][64][40];    // 15360 B

    const int tid  = threadIdx.x;
    const int w    = tid >> 6;
    const int lane = tid & 63;
    const int lr   = lane & 15;      // frag row (m or n)
    const int lg   = lane >> 4;      // k-chunk 0..3
    const int w32  = w * 32;

    const int srow = tid >> 2;       // 0..63
    const int skb  = tid & 3;        // col-chunk of 8 floats

    f32x4 acc[2][4];
#pragma unroll
    for (int mf = 0; mf < 2; ++mf)
#pragma unroll
        for (int nf = 0; nf < 4; ++nf)
#pragma unroll
            for (int r = 0; r < 4; ++r) acc[mf][nf][r] = 0.f;

    float4 ara[2], arb[2], wra, wrb;  // staged fp32 (A 2 row-halves, W 1 row)

    // prologue: tile-0 loads
#pragma unroll
    for (int p = 0; p < 2; ++p) {
        const float* src = A + (size_t)(m0 + p * 64 + srow) * DMODEL + skb * 8;
        ara[p] = *reinterpret_cast<const float4*>(src);
        arb[p] = *reinterpret_cast<const float4*>(src + 4);
    }
    {
        const float* src = W + (size_t)(n0 + srow) * DMODEL + skb * 8;
        wra = *reinterpret_cast<const float4*>(src);
        wrb = *reinterpret_cast<const float4*>(src + 4);
    }

    for (int k0 = 0; k0 < DMODEL; k0 += 32) {
        // convert staged fp32 -> 3 bf16 planes in LDS
#pragma unroll
        for (int p = 0; p < 2; ++p) {
            const int row = p * 64 + srow;
            short8b o1, o2, o3;
            cvt8(ara[p], arb[p], o1, o2, o3);
            *reinterpret_cast<short8b*>(&As[0][row][skb * 8]) = o1;
            *reinterpret_cast<short8b*>(&As[1][row][skb * 8]) = o2;
            *reinterpret_cast<short8b*>(&As[2][row][skb * 8]) = o3;
        }
        {
            short8b o1, o2, o3;
            cvt8(wra, wrb, o1, o2, o3);
            *reinterpret_cast<short8b*>(&Ws[0][srow][skb * 8]) = o1;
            *reinterpret_cast<short8b*>(&Ws[1][srow][skb * 8]) = o2;
            *reinterpret_cast<short8b*>(&Ws[2][srow][skb * 8]) = o3;
        }
        __syncthreads();

        // issue next tile's loads (latency hides under MFMA phase)
        if (k0 + 32 < DMODEL) {
#pragma unroll
            for (int p = 0; p < 2; ++p) {
                const float* src =
                    A + (size_t)(m0 + p * 64 + srow) * DMODEL + k0 + 32 + skb * 8;
                ara[p] = *reinterpret_cast<const float4*>(src);
                arb[p] = *reinterpret_cast<const float4*>(src + 4);
            }
            const float* src = W + (size_t)(n0 + srow) * DMODEL + k0 + 32 + skb * 8;
            wra = *reinterpret_cast<const float4*>(src);
            wrb = *reinterpret_cast<const float4*>(src + 4);
        }

        short8b af[2][3];
#pragma unroll
        for (int mf = 0; mf < 2; ++mf) {
            const int row = w32 + mf * 16 + lr;
#pragma unroll
            for (int p = 0; p < 3; ++p)
                af[mf][p] = *reinterpret_cast<const short8b*>(&As[p][row][lg * 8]);
        }
#pragma unroll
        for (int nf = 0; nf < 4; ++nf) {
            const int row = nf * 16 + lr;
            const short8b b1 = *reinterpret_cast<const short8b*>(&Ws[0][row][lg * 8]);
            const short8b b2 = *reinterpret_cast<const short8b*>(&Ws[1][row][lg * 8]);
            const short8b b3 = *reinterpret_cast<const short8b*>(&Ws[2][row][lg * 8]);
#pragma unroll
            for (int mf = 0; mf < 2; ++mf) {
                acc[mf][nf] = __builtin_amdgcn_mfma_f32_16x16x32_bf16(af[mf][0], b1, acc[mf][nf], 0, 0, 0);
                acc[mf][nf] = __builtin_amdgcn_mfma_f32_16x16x32_bf16(af[mf][1], b1, acc[mf][nf], 0, 0, 0);
                acc[mf][nf] = __builtin_amdgcn_mfma_f32_16x16x32_bf16(af[mf][0], b2, acc[mf][nf], 0, 0, 0);
                acc[mf][nf] = __builtin_amdgcn_mfma_f32_16x16x32_bf16(af[mf][2], b1, acc[mf][nf], 0, 0, 0);
                acc[mf][nf] = __builtin_amdgcn_mfma_f32_16x16x32_bf16(af[mf][0], b3, acc[mf][nf], 0, 0, 0);
                acc[mf][nf] = __builtin_amdgcn_mfma_f32_16x16x32_bf16(af[mf][1], b2, acc[mf][nf], 0, 0, 0);
            }
        }
        __syncthreads();
    }

    // epilogue: C col = lane&15 (n), row = lg*4 + r (m-local)
#pragma unroll
    for (int nf = 0; nf < 4; ++nf) {
        const int n = n0 + nf * 16 + lr;
        const int h = n >> 6, d = n & 63;
        const float bv_ = bias[n];
#pragma unroll
        for (int mf = 0; mf < 2; ++mf) {
#pragma unroll
            for (int r = 0; r < 4; ++r) {
                const int m = m0 + w32 + mf * 16 + lg * 4 + r;
                const int b = m >> 11, l = m & (LSEQ - 1);
                Out[((size_t)(b * NH + h) * LSEQ + l) * DHD + d] = acc[mf][nf][r] + bv_;
            }
        }
    }
}

// ---------------------------------------------------------------------------
// K2: sampled sparsity measure + zero-init of headmask/VmeanRaw.
// v2: 16 lanes cooperatively load one sampled K row (coalesced 256B per
// group-instruction, 4 rows/inst) instead of 1 lane x 16 scattered 16B
// reads -> 4x fewer, 4x larger transactions. Group-shuffle reduce.
// ---------------------------------------------------------------------------
__global__ __launch_bounds__(256) void score_kernel(
    const float* __restrict__ Qt, const float* __restrict__ Kt,
    const int* __restrict__ idxs, float* __restrict__ M,
    unsigned* __restrict__ headmask, float* __restrict__ VmeanRaw)
{
    const int flat = blockIdx.x;             // 16384 blocks
    if (flat < 32) headmask[flat * 256 + threadIdx.x] = 0u;
    else if (flat < 40) VmeanRaw[(flat - 32) * 256 + threadIdx.x] = 0.f;

    const int xcd  = flat & 7;
    const int slot = flat >> 3;              // 0..2047
    const int bh   = xcd * 4 + (slot >> 9);  // 4 bh per XCD, L2-resident K
    const int w    = threadIdx.x >> 6;       // wave = one query row
    const int lane = threadIdx.x & 63;
    const int l    = (slot & 511) * 4 + w;

    const int g  = lane >> 4;                // sample group 0..3
    const int dl = lane & 15;                // d-chunk within group

    const float4 q4 = *reinterpret_cast<const float4*>(
        Qt + ((size_t)bh * LSEQ + l) * DHD + dl * 4);

    const float* Kb = Kt + (size_t)bh * LSEQ * DHD;
    float vmax = -FLT_MAX, vsum = 0.f;
#pragma unroll
    for (int it = 0; it < 10; ++it) {
        const int s = it * 4 + g;
        const int ks = idxs[l * NSAMP + s];
        const float4 k4 = *reinterpret_cast<const float4*>(
            Kb + (size_t)ks * DHD + dl * 4);
        float p = q4.x * k4.x + q4.y * k4.y + q4.z * k4.z + q4.w * k4.w;
        p += __shfl_xor(p, 1);
        p += __shfl_xor(p, 2);
        p += __shfl_xor(p, 4);
        p += __shfl_xor(p, 8);
        vmax = fmaxf(vmax, p);
        vsum += p;
    }
    vmax = fmaxf(vmax, __shfl_xor(vmax, 16));
    vsum += __shfl_xor(vsum, 16);
    vmax = fmaxf(vmax, __shfl_xor(vmax, 32));
    vsum += __shfl_xor(vsum, 32);
    if (lane == 0) M[(size_t)bh * LSEQ + l] = vmax - vsum * (1.0f / LSEQ);
}

// ---------------------------------------------------------------------------
// K3: stable top-40 per (b,h); candidates in registers.
// ---------------------------------------------------------------------------
__global__ __launch_bounds__(256) void topk_kernel(
    const float* __restrict__ M, int* __restrict__ topidx,
    unsigned* __restrict__ headmask, unsigned char* __restrict__ slot)
{
    const int bh = blockIdx.x;
    const int b = bh >> 3, h = bh & 7;
    const int w = threadIdx.x >> 6, lane = threadIdx.x & 63;
    const int base = threadIdx.x * 8;

    float e[8];
    {
        const float4 v0 = *reinterpret_cast<const float4*>(M + (size_t)bh * LSEQ + base);
        const float4 v1 = *reinterpret_cast<const float4*>(M + (size_t)bh * LSEQ + base + 4);
        e[0] = v0.x; e[1] = v0.y; e[2] = v0.z; e[3] = v0.w;
        e[4] = v1.x; e[5] = v1.y; e[6] = v1.z; e[7] = v1.w;
    }

    __shared__ float rv[4];
    __shared__ int   ri[4];
    __shared__ int   winner;

    for (int t = 0; t < NTOP; ++t) {
        float bv = e[0]; int br = 0;
#pragma unroll
        for (int r = 1; r < 8; ++r)
            if (e[r] > bv) { bv = e[r]; br = r; }
        int bi = base + br;
#pragma unroll
        for (int off = 32; off; off >>= 1) {
            const float ov = __shfl_xor(bv, off);
            const int   oi = __shfl_xor(bi, off);
            if (ov > bv || (ov == bv && oi < bi)) { bv = ov; bi = oi; }
        }
        if (lane == 0) { rv[w] = bv; ri[w] = bi; }
        __syncthreads();
        if (threadIdx.x == 0) {
            float fv = rv[0]; int fi = ri[0];
#pragma unroll
            for (int k = 1; k < 4; ++k)
                if (rv[k] > fv || (rv[k] == fv && ri[k] < fi)) { fv = rv[k]; fi = ri[k]; }
            topidx[bh * NTOP + t] = fi;
            atomicOr(&headmask[b * LSEQ + fi], 1u << h);
            slot[bh * LSEQ + fi] = (unsigned char)t;
            winner = fi;
        }
        __syncthreads();
        const int fi = winner;
        if ((fi >> 3) == threadIdx.x) e[fi & 7] = -FLT_MAX;
    }
}

// ---------------------------------------------------------------------------
// K4: flash split-K attention partials + V column-sum accumulation.
// ---------------------------------------------------------------------------
__global__ __launch_bounds__(256) void attn_partial(
    const float* __restrict__ Qt, const float* __restrict__ Kt,
    const float* __restrict__ Vt, const int* __restrict__ topidx,
    float* __restrict__ psums, float* __restrict__ pacc,
    float* __restrict__ VmeanRaw)
{
    const int bh = blockIdx.x;
    const int c  = blockIdx.y;
    const int kbase = c * TK;
    const int tid = threadIdx.x;

    __shared__ float Qs[NTOP][DHD];
    __shared__ float Ks[TK][68];
    __shared__ float Vs[TK][68];
    __shared__ float Sc[TK][52];

    for (int i = tid; i < NTOP * DHD; i += 256) {
        const int q = i >> 6, d = i & 63;
        const int row = topidx[bh * NTOP + q];
        Qs[q][d] = Qt[((size_t)bh * LSEQ + row) * DHD + d];
    }
    {
        const int r0 = tid >> 4, c4 = tid & 15;
#pragma unroll
        for (int rr = 0; rr < 4; ++rr) {
            const int r = r0 + rr * 16;
            const size_t g = ((size_t)bh * LSEQ + kbase + r) * DHD + c4 * 4;
            *reinterpret_cast<float4*>(&Ks[r][c4 * 4]) =
                *reinterpret_cast<const float4*>(Kt + g);
            *reinterpret_cast<float4*>(&Vs[r][c4 * 4]) =
                *reinterpret_cast<const float4*>(Vt + g);
        }
    }
    __syncthreads();

    {
        const int d = tid & 63, part = tid >> 6;
        float s = 0.f;
#pragma unroll
        for (int i = 0; i < 16; ++i) s += Vs[part * 16 + i][d];
        atomicAdd(&VmeanRaw[bh * DHD + d], s);
    }

    {
        const int kloc = tid & 15, qg = tid >> 4;
#pragma unroll
        for (int qit = 0; qit < 3; ++qit) {
            const int q = qg + qit * 16;
            if (q < NTOP) {
#pragma unroll
                for (int kb = 0; kb < 4; ++kb) {
                    const int k = kloc + kb * 16;
                    float acc = 0.f;
#pragma unroll
                    for (int j = 0; j < 16; ++j) {
                        const float4 kv = *reinterpret_cast<const float4*>(&Ks[k][j * 4]);
                        const float4 qv = *reinterpret_cast<const float4*>(&Qs[q][j * 4]);
                        acc += qv.x * kv.x + qv.y * kv.y + qv.z * kv.z + qv.w * kv.w;
                    }
                    Sc[k][q] = acc * QK_SCALE;
                }
            }
        }
    }
    __syncthreads();

    {
        const int w = tid >> 6, lane = tid & 63;
#pragma unroll
        for (int j = 0; j < 10; ++j) {
            const int q = w * 10 + j;
            const float ee = __expf(Sc[lane][q]);
            float s = ee;
#pragma unroll
            for (int off = 32; off; off >>= 1) s += __shfl_xor(s, off);
            Sc[lane][q] = ee;
            if (lane == 0) psums[((size_t)bh * NCHUNK + c) * NTOP + q] = s;
        }
    }
    __syncthreads();

    {
        const int d = tid & 63, g = tid >> 6;
        const int q0 = g * 12;
        const int nq = (g < 3) ? 12 : 4;
        float acc[12] = {};
        for (int k = 0; k < TK; ++k) {
            const float v = Vs[k][d];
            const float4 s0 = *reinterpret_cast<const float4*>(&Sc[k][q0]);
            acc[0] = fmaf(s0.x, v, acc[0]); acc[1] = fmaf(s0.y, v, acc[1]);
            acc[2] = fmaf(s0.z, v, acc[2]); acc[3] = fmaf(s0.w, v, acc[3]);
            if (g < 3) {
                const float4 s1 = *reinterpret_cast<const float4*>(&Sc[k][q0 + 4]);
                const float4 s2 = *reinterpret_cast<const float4*>(&Sc[k][q0 + 8]);
                acc[4] = fmaf(s1.x, v, acc[4]); acc[5]  = fmaf(s1.y, v, acc[5]);
                acc[6] = fmaf(s1.z, v, acc[6]); acc[7]  = fmaf(s1.w, v, acc[7]);
                acc[8] = fmaf(s2.x, v, acc[8]); acc[9]  = fmaf(s2.y, v, acc[9]);
                acc[10] = fmaf(s2.z, v, acc[10]); acc[11] = fmaf(s2.w, v, acc[11]);
            }
        }
#pragma unroll
        for (int j = 0; j < 12; ++j)
            if (j < nq)
                pacc[(((size_t)bh * NCHUNK + c) * NTOP + q0 + j) * DHD + d] = acc[j];
    }
}

// ---------------------------------------------------------------------------
// K5: combine partials -> delta; bh%8==0 blocks also compute meanout.
// ---------------------------------------------------------------------------
__global__ __launch_bounds__(256) void attn_combine(
    const float* __restrict__ psums, const float* __restrict__ pacc,
    const float* __restrict__ VmeanRaw, const float* __restrict__ Wo,
    const float* __restrict__ bo, float* __restrict__ delta,
    float* __restrict__ meanout)
{
    const int bh = blockIdx.x;
    __shared__ float winv[NTOP];
    __shared__ float mc[DMODEL];
    if (threadIdx.x < NTOP) {
        float s = 0.f;
        for (int c = 0; c < NCHUNK; ++c)
            s += psums[((size_t)bh * NCHUNK + c) * NTOP + threadIdx.x];
        winv[threadIdx.x] = 1.0f / s;
    }
    __syncthreads();
    const int d = threadIdx.x & 63, g = threadIdx.x >> 6;
    const float vm = VmeanRaw[bh * DHD + d] * (1.0f / (float)LSEQ);
    for (int q = g; q < NTOP; q += 4) {
        float a = 0.f;
        for (int c = 0; c < NCHUNK; ++c)
            a += pacc[(((size_t)bh * NCHUNK + c) * NTOP + q) * DHD + d];
        delta[((size_t)bh * NTOP + q) * DHD + d] = a * winv[q] - vm;
    }

    if ((bh & 7) == 0) {
        const int b = bh >> 3;
        for (int i = threadIdx.x; i < DMODEL; i += 256)
            mc[i] = VmeanRaw[b * DMODEL + i] * (1.0f / (float)LSEQ);
        __syncthreads();
        for (int n = threadIdx.x; n < DMODEL; n += 256) {
            float acc = bo[n];
            const float* wr = Wo + (size_t)n * DMODEL;
            for (int k = 0; k < DMODEL; ++k) acc = fmaf(mc[k], wr[k], acc);
            meanout[b * DMODEL + n] = acc;
        }
    }
}

// ---------------------------------------------------------------------------
// K6: final output rows; 128 threads, float4 path.
// ---------------------------------------------------------------------------
__global__ __launch_bounds__(128) void out_kernel(
    const float* __restrict__ meanout, const unsigned* __restrict__ headmask,
    const unsigned char* __restrict__ slot, const float* __restrict__ delta,
    const float* __restrict__ Wo, float* __restrict__ out)
{
    const int rowg = blockIdx.x;
    const int b = rowg >> 11, lloc = rowg & (LSEQ - 1);
    const unsigned mask = headmask[rowg];

    __shared__ float dl[NH][DHD];
    if (threadIdx.x < DHD) {
        for (int h = 0; h < NH; ++h) {
            if ((mask >> h) & 1) {
                const int bh = b * NH + h;
                const int u = slot[bh * LSEQ + lloc];
                dl[h][threadIdx.x] = delta[((size_t)bh * NTOP + u) * DHD + threadIdx.x];
            }
        }
    }
    __syncthreads();

    const int n4 = threadIdx.x;
    float4 val = *reinterpret_cast<const float4*>(meanout + b * DMODEL + n4 * 4);
    unsigned mm = mask;
    while (mm) {
        const int h = __ffs(mm) - 1;
        mm &= mm - 1;
#pragma unroll
        for (int c = 0; c < 4; ++c) {
            const int n = n4 * 4 + c;
            const float4* wr4 = reinterpret_cast<const float4*>(
                Wo + (size_t)n * DMODEL + h * DHD);
            float a = 0.f;
#pragma unroll
            for (int dd = 0; dd < 16; ++dd) {
                const float4 wv = wr4[dd];
                a += dl[h][dd * 4 + 0] * wv.x + dl[h][dd * 4 + 1] * wv.y +
                     dl[h][dd * 4 + 2] * wv.z + dl[h][dd * 4 + 3] * wv.w;
            }
            (&val.x)[c] += a;
        }
    }
    *reinterpret_cast<float4*>(out + (size_t)rowg * DMODEL + n4 * 4) = val;
}

// ---------------------------------------------------------------------------
extern "C" void kernel_launch(void* const* d_in, const int* in_sizes, int n_in,
                              void* d_out, int out_size, void* d_ws, size_t ws_size,
                              hipStream_t stream)
{
    (void)in_sizes; (void)n_in; (void)out_size; (void)ws_size;
    const float* x     = (const float*)d_in[0];
    const float* ctxin = (const float*)d_in[1];
    const float* Wq    = (const float*)d_in[2];
    const float* bq    = (const float*)d_in[3];
    const float* Wk    = (const float*)d_in[4];
    const float* bk    = (const float*)d_in[5];
    const float* Wv    = (const float*)d_in[6];
    const float* bv    = (const float*)d_in[7];
    const float* Wo    = (const float*)d_in[8];
    const float* bo    = (const float*)d_in[9];
    const int*   idxs  = (const int*)d_in[10];
    float* out = (float*)d_out;

    char* ws = (char*)d_ws;
    size_t off = 0;
    auto alloc = [&](size_t bytes) -> void* {
        void* p = ws + off;
        off += (bytes + 255) & ~(size_t)255;
        return p;
    };

    const size_t qkv_bytes = (size_t)BATCH * NH * LSEQ * DHD * sizeof(float);
    float*         Qt       = (float*)alloc(qkv_bytes);
    float*         Kt       = (float*)alloc(qkv_bytes);
    float*         Vt       = (float*)alloc(qkv_bytes);
    float*         Mbuf     = (float*)alloc((size_t)BATCH * NH * LSEQ * sizeof(float));
    float*         VmeanRaw = (float*)alloc((size_t)BATCH * NH * DHD * sizeof(float));
    float*         meanout  = (float*)alloc((size_t)BATCH * DMODEL * sizeof(float));
    float*         delta    = (float*)alloc((size_t)BATCH * NH * NTOP * DHD * sizeof(float));
    int*           topidx   = (int*)alloc((size_t)BATCH * NH * NTOP * sizeof(int));
    unsigned*      headmask = (unsigned*)alloc((size_t)BATCH * LSEQ * sizeof(unsigned));
    unsigned char* slot     = (unsigned char*)alloc((size_t)BATCH * NH * LSEQ);
    float*         psums    = (float*)alloc((size_t)BATCH * NH * NCHUNK * NTOP * sizeof(float));
    float*         pacc     = (float*)alloc((size_t)BATCH * NH * NCHUNK * NTOP * DHD * sizeof(float));

    qkv_gemm_mfma<<<dim3(512, 3), 256, 0, stream>>>(
        x, ctxin, Wq, Wk, Wv, bq, bk, bv, Qt, Kt, Vt);

    score_kernel<<<(BATCH * NH * LSEQ) / 4, 256, 0, stream>>>(
        Qt, Kt, idxs, Mbuf, headmask, VmeanRaw);

    topk_kernel<<<BATCH * NH, 256, 0, stream>>>(Mbuf, topidx, headmask, slot);

    attn_partial<<<dim3(BATCH * NH, NCHUNK), 256, 0, stream>>>(
        Qt, Kt, Vt, topidx, psums, pacc, VmeanRaw);

    attn_combine<<<BATCH * NH, 256, 0, stream>>>(
        psums, pacc, VmeanRaw, Wo, bo, delta, meanout);

    out_kernel<<<BATCH * LSEQ, 128, 0, stream>>>(
        meanout, headmask, slot, delta, Wo, out);
}

// Round 10
// 314.836 us; speedup vs baseline: 1.7390x; 1.0687x over previous
//
#include <hip/hip_runtime.h>
#include <float.h>

#define BATCH 4
#define LSEQ  2048
#define DMODEL 512
#define NH    8
#define DHD   64
#define NSAMP 40
#define NTOP  40
#define NCHUNK 32
#define TK    64
#define QK_SCALE 0.125f

typedef unsigned short u16;
typedef __attribute__((ext_vector_type(8))) short short8b;  // 8 bf16 = 16 B
typedef __attribute__((ext_vector_type(4))) float f32x4;

#define ASTRIDE ((size_t)BATCH * LSEQ * DMODEL)   // 4,194,304 elems (2^22)
#define WSTRIDE ((size_t)DMODEL * DMODEL)         //   262,144 elems (2^18)

// RTNE float->bf16 on raw bits (inputs finite).
static __device__ __forceinline__ u16 f2bf(float x) {
    unsigned u = __float_as_uint(x);
    u += 0x7FFFu + ((u >> 16) & 1u);
    return (u16)(u >> 16);
}
static __device__ __forceinline__ float bf2f(u16 s) {
    return __uint_as_float((unsigned)s << 16);
}

// ---------------------------------------------------------------------------
// K0: unified 3-way bf16 split, ONE dispatch. x = p1+p2+p3 + O(2^-27|x|).
// ---------------------------------------------------------------------------
__global__ __launch_bounds__(256) void split3_all(
    const float* __restrict__ x, const float* __restrict__ ctxin,
    const float* __restrict__ Wq, const float* __restrict__ Wk,
    const float* __restrict__ Wv,
    u16* __restrict__ xsP, u16* __restrict__ csP,
    u16* __restrict__ wqP, u16* __restrict__ wkP, u16* __restrict__ wvP)
{
    const int X4 = 1 << 20;                 // float4s in x / ctx
    const int W4 = 1 << 16;                 // float4s in each W
    const int total = 2 * X4 + 3 * W4;
    for (int i = blockIdx.x * 256 + threadIdx.x; i < total; i += gridDim.x * 256) {
        const float* src; u16* dst; size_t pstride; int i4;
        if (i < X4)            { src = x;     dst = xsP; pstride = ASTRIDE; i4 = i; }
        else if (i < 2 * X4)   { src = ctxin; dst = csP; pstride = ASTRIDE; i4 = i - X4; }
        else {
            const int w = i - 2 * X4;
            const int which = w >> 16, rem = w & (W4 - 1);
            src = (which == 0) ? Wq : (which == 1) ? Wk : Wv;
            dst = (which == 0) ? wqP : (which == 1) ? wkP : wvP;
            pstride = WSTRIDE; i4 = rem;
        }
        const float4 v = reinterpret_cast<const float4*>(src)[i4];
        const float in[4] = {v.x, v.y, v.z, v.w};
        ushort4 o1, o2, o3;
        u16 b1[4], b2[4], b3[4];
#pragma unroll
        for (int c = 0; c < 4; ++c) {
            const float xx = in[c];
            b1[c] = f2bf(xx);
            const float r1 = xx - bf2f(b1[c]);
            b2[c] = f2bf(r1);
            b3[c] = f2bf(r1 - bf2f(b2[c]));
        }
        o1.x = b1[0]; o1.y = b1[1]; o1.z = b1[2]; o1.w = b1[3];
        o2.x = b2[0]; o2.y = b2[1]; o2.z = b2[2]; o2.w = b2[3];
        o3.x = b3[0]; o3.y = b3[1]; o3.z = b3[2]; o3.w = b3[3];
        reinterpret_cast<ushort4*>(dst)[i4]                = o1;
        reinterpret_cast<ushort4*>(dst + pstride)[i4]      = o2;
        reinterpret_cast<ushort4*>(dst + 2 * pstride)[i4]  = o3;
    }
}

// ---------------------------------------------------------------------------
// K1: QKV GEMM on MFMA, bf16x3 pre-split planes (6 products: 11,12,21,13,
// 31,22 — fp32-GEMM-level accuracy). C = A @ W^T + b.
// v4: tile 128m x 128n, 4 waves 2x2, wave tile 64x64 (96 MFMA / 24 ds_read
// per K-tile). FIX vs v3: each thread stages 16 bf16 (TWO short8b) per
// plane per matrix — v3 staged only 8, leaving LDS cols 8-15/24-31
// uninitialized -> NaN. Pad-40 rows: 2-way banks. XCD-chunked decode.
// ---------------------------------------------------------------------------
__global__ __launch_bounds__(256) void qkv_gemm_mfma(
    const u16* __restrict__ xsP, const u16* __restrict__ csP,
    const u16* __restrict__ wqP, const u16* __restrict__ wkP,
    const u16* __restrict__ wvP,
    const float* __restrict__ bq, const float* __restrict__ bk,
    const float* __restrict__ bv,
    float* __restrict__ Qt, float* __restrict__ Kt, float* __restrict__ Vt)
{
    const int z = blockIdx.y;
    const int i = blockIdx.x;            // 0..255
    const int xcd = i & 7;
    const int loc = i >> 3;              // 0..31
    const int m0 = (xcd * 8 + (loc & 7)) * 128;
    const int n0 = (loc >> 3) * 128;

    const u16* __restrict__ Ap   = (z == 0) ? xsP : csP;
    const u16* __restrict__ Wp   = (z == 0) ? wqP : (z == 1 ? wkP : wvP);
    const float* __restrict__ bias = (z == 0) ? bq : (z == 1 ? bk : bv);
    float*       __restrict__ Out  = (z == 0) ? Qt : (z == 1 ? Kt : Vt);

    __shared__ u16 As[3][128][40];   // 30720 B
    __shared__ u16 Ws[3][128][40];   // 30720 B

    const int tid  = threadIdx.x;
    const int w    = tid >> 6;
    const int lane = tid & 63;
    const int wm   = w >> 1;         // 0..1
    const int wn   = w & 1;          // 0..1
    const int lr   = lane & 15;
    const int lg   = lane >> 4;

    const int srow = tid >> 1;       // 0..127
    const int sc   = (tid & 1) * 16; // k half-row base (16 bf16 = 2 short8b)

    f32x4 acc[4][4];
#pragma unroll
    for (int mf = 0; mf < 4; ++mf)
#pragma unroll
        for (int nf = 0; nf < 4; ++nf)
#pragma unroll
            for (int r = 0; r < 4; ++r) acc[mf][nf][r] = 0.f;

    short8b sa[3][2], sw[3][2];
    // prologue: tile-0 loads (16 bf16 per plane per matrix per thread)
#pragma unroll
    for (int p = 0; p < 3; ++p) {
        const u16* asrc = Ap + p * ASTRIDE + (size_t)(m0 + srow) * DMODEL + sc;
        const u16* wsrc = Wp + p * WSTRIDE + (size_t)(n0 + srow) * DMODEL + sc;
        sa[p][0] = *reinterpret_cast<const short8b*>(asrc);
        sa[p][1] = *reinterpret_cast<const short8b*>(asrc + 8);
        sw[p][0] = *reinterpret_cast<const short8b*>(wsrc);
        sw[p][1] = *reinterpret_cast<const short8b*>(wsrc + 8);
    }

    for (int k0 = 0; k0 < DMODEL; k0 += 32) {
        // write staged regs -> LDS (full coverage: rows 0..127, cols 0..31)
#pragma unroll
        for (int p = 0; p < 3; ++p) {
            *reinterpret_cast<short8b*>(&As[p][srow][sc])     = sa[p][0];
            *reinterpret_cast<short8b*>(&As[p][srow][sc + 8]) = sa[p][1];
            *reinterpret_cast<short8b*>(&Ws[p][srow][sc])     = sw[p][0];
            *reinterpret_cast<short8b*>(&Ws[p][srow][sc + 8]) = sw[p][1];
        }
        __syncthreads();

        // issue next tile's loads (hide under MFMA phase)
        if (k0 + 32 < DMODEL) {
#pragma unroll
            for (int p = 0; p < 3; ++p) {
                const u16* asrc =
                    Ap + p * ASTRIDE + (size_t)(m0 + srow) * DMODEL + k0 + 32 + sc;
                const u16* wsrc =
                    Wp + p * WSTRIDE + (size_t)(n0 + srow) * DMODEL + k0 + 32 + sc;
                sa[p][0] = *reinterpret_cast<const short8b*>(asrc);
                sa[p][1] = *reinterpret_cast<const short8b*>(asrc + 8);
                sw[p][0] = *reinterpret_cast<const short8b*>(wsrc);
                sw[p][1] = *reinterpret_cast<const short8b*>(wsrc + 8);
            }
        }

        short8b af[4][3];
#pragma unroll
        for (int mf = 0; mf < 4; ++mf) {
            const int row = wm * 64 + mf * 16 + lr;
#pragma unroll
            for (int p = 0; p < 3; ++p)
                af[mf][p] = *reinterpret_cast<const short8b*>(&As[p][row][lg * 8]);
        }
#pragma unroll
        for (int nf = 0; nf < 4; ++nf) {
            const int row = wn * 64 + nf * 16 + lr;
            const short8b b1 = *reinterpret_cast<const short8b*>(&Ws[0][row][lg * 8]);
            const short8b b2 = *reinterpret_cast<const short8b*>(&Ws[1][row][lg * 8]);
            const short8b b3 = *reinterpret_cast<const short8b*>(&Ws[2][row][lg * 8]);
#pragma unroll
            for (int mf = 0; mf < 4; ++mf) {
                acc[mf][nf] = __builtin_amdgcn_mfma_f32_16x16x32_bf16(af[mf][0], b1, acc[mf][nf], 0, 0, 0);
                acc[mf][nf] = __builtin_amdgcn_mfma_f32_16x16x32_bf16(af[mf][1], b1, acc[mf][nf], 0, 0, 0);
                acc[mf][nf] = __builtin_amdgcn_mfma_f32_16x16x32_bf16(af[mf][0], b2, acc[mf][nf], 0, 0, 0);
                acc[mf][nf] = __builtin_amdgcn_mfma_f32_16x16x32_bf16(af[mf][2], b1, acc[mf][nf], 0, 0, 0);
                acc[mf][nf] = __builtin_amdgcn_mfma_f32_16x16x32_bf16(af[mf][0], b3, acc[mf][nf], 0, 0, 0);
                acc[mf][nf] = __builtin_amdgcn_mfma_f32_16x16x32_bf16(af[mf][1], b2, acc[mf][nf], 0, 0, 0);
            }
        }
        __syncthreads();
    }

    // epilogue: C col = lane&15 (n), row = lg*4 + r (m-local)
#pragma unroll
    for (int nf = 0; nf < 4; ++nf) {
        const int n = n0 + wn * 64 + nf * 16 + lr;
        const int h = n >> 6, d = n & 63;
        const float bv_ = bias[n];
#pragma unroll
        for (int mf = 0; mf < 4; ++mf) {
#pragma unroll
            for (int r = 0; r < 4; ++r) {
                const int m = m0 + wm * 64 + mf * 16 + lg * 4 + r;
                const int b = m >> 11, l = m & (LSEQ - 1);
                Out[((size_t)(b * NH + h) * LSEQ + l) * DHD + d] = acc[mf][nf][r] + bv_;
            }
        }
    }
}

// ---------------------------------------------------------------------------
// K2: sampled sparsity measure + zero-init of headmask/VmeanRaw.
// 16-lane cooperative row loads (coalesced 256B); group-shuffle reduce.
// ---------------------------------------------------------------------------
__global__ __launch_bounds__(256) void score_kernel(
    const float* __restrict__ Qt, const float* __restrict__ Kt,
    const int* __restrict__ idxs, float* __restrict__ M,
    unsigned* __restrict__ headmask, float* __restrict__ VmeanRaw)
{
    const int flat = blockIdx.x;             // 16384 blocks
    if (flat < 32) headmask[flat * 256 + threadIdx.x] = 0u;
    else if (flat < 40) VmeanRaw[(flat - 32) * 256 + threadIdx.x] = 0.f;

    const int xcd  = flat & 7;
    const int slot = flat >> 3;              // 0..2047
    const int bh   = xcd * 4 + (slot >> 9);  // 4 bh per XCD, K L2-resident
    const int w    = threadIdx.x >> 6;
    const int lane = threadIdx.x & 63;
    const int l    = (slot & 511) * 4 + w;

    const int g  = lane >> 4;
    const int dl = lane & 15;

    const float4 q4 = *reinterpret_cast<const float4*>(
        Qt + ((size_t)bh * LSEQ + l) * DHD + dl * 4);

    const float* Kb = Kt + (size_t)bh * LSEQ * DHD;
    float vmax = -FLT_MAX, vsum = 0.f;
#pragma unroll
    for (int it = 0; it < 10; ++it) {
        const int s = it * 4 + g;
        const int ks = idxs[l * NSAMP + s];
        const float4 k4 = *reinterpret_cast<const float4*>(
            Kb + (size_t)ks * DHD + dl * 4);
        float p = q4.x * k4.x + q4.y * k4.y + q4.z * k4.z + q4.w * k4.w;
        p += __shfl_xor(p, 1);
        p += __shfl_xor(p, 2);
        p += __shfl_xor(p, 4);
        p += __shfl_xor(p, 8);
        vmax = fmaxf(vmax, p);
        vsum += p;
    }
    vmax = fmaxf(vmax, __shfl_xor(vmax, 16));
    vsum += __shfl_xor(vsum, 16);
    vmax = fmaxf(vmax, __shfl_xor(vmax, 32));
    vsum += __shfl_xor(vsum, 32);
    if (lane == 0) M[(size_t)bh * LSEQ + l] = vmax - vsum * (1.0f / LSEQ);
}

// ---------------------------------------------------------------------------
// K3: stable top-40 per (b,h); candidates in registers.
// ---------------------------------------------------------------------------
__global__ __launch_bounds__(256) void topk_kernel(
    const float* __restrict__ M, int* __restrict__ topidx,
    unsigned* __restrict__ headmask, unsigned char* __restrict__ slot)
{
    const int bh = blockIdx.x;
    const int b = bh >> 3, h = bh & 7;
    const int w = threadIdx.x >> 6, lane = threadIdx.x & 63;
    const int base = threadIdx.x * 8;

    float e[8];
    {
        const float4 v0 = *reinterpret_cast<const float4*>(M + (size_t)bh * LSEQ + base);
        const float4 v1 = *reinterpret_cast<const float4*>(M + (size_t)bh * LSEQ + base + 4);
        e[0] = v0.x; e[1] = v0.y; e[2] = v0.z; e[3] = v0.w;
        e[4] = v1.x; e[5] = v1.y; e[6] = v1.z; e[7] = v1.w;
    }

    __shared__ float rv[4];
    __shared__ int   ri[4];
    __shared__ int   winner;

    for (int t = 0; t < NTOP; ++t) {
        float bv = e[0]; int br = 0;
#pragma unroll
        for (int r = 1; r < 8; ++r)
            if (e[r] > bv) { bv = e[r]; br = r; }
        int bi = base + br;
#pragma unroll
        for (int off = 32; off; off >>= 1) {
            const float ov = __shfl_xor(bv, off);
            const int   oi = __shfl_xor(bi, off);
            if (ov > bv || (ov == bv && oi < bi)) { bv = ov; bi = oi; }
        }
        if (lane == 0) { rv[w] = bv; ri[w] = bi; }
        __syncthreads();
        if (threadIdx.x == 0) {
            float fv = rv[0]; int fi = ri[0];
#pragma unroll
            for (int k = 1; k < 4; ++k)
                if (rv[k] > fv || (rv[k] == fv && ri[k] < fi)) { fv = rv[k]; fi = ri[k]; }
            topidx[bh * NTOP + t] = fi;
            atomicOr(&headmask[b * LSEQ + fi], 1u << h);
            slot[bh * LSEQ + fi] = (unsigned char)t;
            winner = fi;
        }
        __syncthreads();
        const int fi = winner;
        if ((fi >> 3) == threadIdx.x) e[fi & 7] = -FLT_MAX;
    }
}

// ---------------------------------------------------------------------------
// K4: flash split-K attention partials + V column-sum accumulation.
// ---------------------------------------------------------------------------
__global__ __launch_bounds__(256) void attn_partial(
    const float* __restrict__ Qt, const float* __restrict__ Kt,
    const float* __restrict__ Vt, const int* __restrict__ topidx,
    float* __restrict__ psums, float* __restrict__ pacc,
    float* __restrict__ VmeanRaw)
{
    const int bh = blockIdx.x;
    const int c  = blockIdx.y;
    const int kbase = c * TK;
    const int tid = threadIdx.x;

    __shared__ float Qs[NTOP][DHD];
    __shared__ float Ks[TK][68];
    __shared__ float Vs[TK][68];
    __shared__ float Sc[TK][52];

    for (int i = tid; i < NTOP * DHD; i += 256) {
        const int q = i >> 6, d = i & 63;
        const int row = topidx[bh * NTOP + q];
        Qs[q][d] = Qt[((size_t)bh * LSEQ + row) * DHD + d];
    }
    {
        const int r0 = tid >> 4, c4 = tid & 15;
#pragma unroll
        for (int rr = 0; rr < 4; ++rr) {
            const int r = r0 + rr * 16;
            const size_t g = ((size_t)bh * LSEQ + kbase + r) * DHD + c4 * 4;
            *reinterpret_cast<float4*>(&Ks[r][c4 * 4]) =
                *reinterpret_cast<const float4*>(Kt + g);
            *reinterpret_cast<float4*>(&Vs[r][c4 * 4]) =
                *reinterpret_cast<const float4*>(Vt + g);
        }
    }
    __syncthreads();

    {
        const int d = tid & 63, part = tid >> 6;
        float s = 0.f;
#pragma unroll
        for (int i = 0; i < 16; ++i) s += Vs[part * 16 + i][d];
        atomicAdd(&VmeanRaw[bh * DHD + d], s);
    }

    {
        const int kloc = tid & 15, qg = tid >> 4;
#pragma unroll
        for (int qit = 0; qit < 3; ++qit) {
            const int q = qg + qit * 16;
            if (q < NTOP) {
#pragma unroll
                for (int kb = 0; kb < 4; ++kb) {
                    const int k = kloc + kb * 16;
                    float acc = 0.f;
#pragma unroll
                    for (int j = 0; j < 16; ++j) {
                        const float4 kv = *reinterpret_cast<const float4*>(&Ks[k][j * 4]);
                        const float4 qv = *reinterpret_cast<const float4*>(&Qs[q][j * 4]);
                        acc += qv.x * kv.x + qv.y * kv.y + qv.z * kv.z + qv.w * kv.w;
                    }
                    Sc[k][q] = acc * QK_SCALE;
                }
            }
        }
    }
    __syncthreads();

    {
        const int w = tid >> 6, lane = tid & 63;
#pragma unroll
        for (int j = 0; j < 10; ++j) {
            const int q = w * 10 + j;
            const float ee = __expf(Sc[lane][q]);
            float s = ee;
#pragma unroll
            for (int off = 32; off; off >>= 1) s += __shfl_xor(s, off);
            Sc[lane][q] = ee;
            if (lane == 0) psums[((size_t)bh * NCHUNK + c) * NTOP + q] = s;
        }
    }
    __syncthreads();

    {
        const int d = tid & 63, g = tid >> 6;
        const int q0 = g * 12;
        const int nq = (g < 3) ? 12 : 4;
        float acc[12] = {};
        for (int k = 0; k < TK; ++k) {
            const float v = Vs[k][d];
            const float4 s0 = *reinterpret_cast<const float4*>(&Sc[k][q0]);
            acc[0] = fmaf(s0.x, v, acc[0]); acc[1] = fmaf(s0.y, v, acc[1]);
            acc[2] = fmaf(s0.z, v, acc[2]); acc[3] = fmaf(s0.w, v, acc[3]);
            if (g < 3) {
                const float4 s1 = *reinterpret_cast<const float4*>(&Sc[k][q0 + 4]);
                const float4 s2 = *reinterpret_cast<const float4*>(&Sc[k][q0 + 8]);
                acc[4] = fmaf(s1.x, v, acc[4]); acc[5]  = fmaf(s1.y, v, acc[5]);
                acc[6] = fmaf(s1.z, v, acc[6]); acc[7]  = fmaf(s1.w, v, acc[7]);
                acc[8] = fmaf(s2.x, v, acc[8]); acc[9]  = fmaf(s2.y, v, acc[9]);
                acc[10] = fmaf(s2.z, v, acc[10]); acc[11] = fmaf(s2.w, v, acc[11]);
            }
        }
#pragma unroll
        for (int j = 0; j < 12; ++j)
            if (j < nq)
                pacc[(((size_t)bh * NCHUNK + c) * NTOP + q0 + j) * DHD + d] = acc[j];
    }
}

// ---------------------------------------------------------------------------
// K5: combine partials -> delta; grid (32 bh, 4 q-quarters). y==0 & bh%8==0
// blocks also compute meanout.
// ---------------------------------------------------------------------------
__global__ __launch_bounds__(256) void attn_combine(
    const float* __restrict__ psums, const float* __restrict__ pacc,
    const float* __restrict__ VmeanRaw, const float* __restrict__ Wo,
    const float* __restrict__ bo, float* __restrict__ delta,
    float* __restrict__ meanout)
{
    const int bh = blockIdx.x;
    const int y  = blockIdx.y;              // q-quarter: q in [y*10, y*10+10)
    __shared__ float winv[10];
    __shared__ float mc[DMODEL];
    if (threadIdx.x < 10) {
        const int q = y * 10 + threadIdx.x;
        float s = 0.f;
        for (int c = 0; c < NCHUNK; ++c)
            s += psums[((size_t)bh * NCHUNK + c) * NTOP + q];
        winv[threadIdx.x] = 1.0f / s;
    }
    __syncthreads();
    const int d = threadIdx.x & 63, g = threadIdx.x >> 6;
    const float vm = VmeanRaw[bh * DHD + d] * (1.0f / (float)LSEQ);
    for (int q = y * 10 + g; q < y * 10 + 10; q += 4) {
        float a = 0.f;
        for (int c = 0; c < NCHUNK; ++c)
            a += pacc[(((size_t)bh * NCHUNK + c) * NTOP + q) * DHD + d];
        delta[((size_t)bh * NTOP + q) * DHD + d] = a * winv[q - y * 10] - vm;
    }

    if (y == 0 && (bh & 7) == 0) {
        const int b = bh >> 3;
        for (int i = threadIdx.x; i < DMODEL; i += 256)
            mc[i] = VmeanRaw[b * DMODEL + i] * (1.0f / (float)LSEQ);
        __syncthreads();
        for (int n = threadIdx.x; n < DMODEL; n += 256) {
            float acc = bo[n];
            const float* wr = Wo + (size_t)n * DMODEL;
            for (int k = 0; k < DMODEL; ++k) acc = fmaf(mc[k], wr[k], acc);
            meanout[b * DMODEL + n] = acc;
        }
    }
}

// ---------------------------------------------------------------------------
// K6: final output rows; 128 threads, float4 path.
// ---------------------------------------------------------------------------
__global__ __launch_bounds__(128) void out_kernel(
    const float* __restrict__ meanout, const unsigned* __restrict__ headmask,
    const unsigned char* __restrict__ slot, const float* __restrict__ delta,
    const float* __restrict__ Wo, float* __restrict__ out)
{
    const int rowg = blockIdx.x;
    const int b = rowg >> 11, lloc = rowg & (LSEQ - 1);
    const unsigned mask = headmask[rowg];

    __shared__ float dl[NH][DHD];
    if (threadIdx.x < DHD) {
        for (int h = 0; h < NH; ++h) {
            if ((mask >> h) & 1) {
                const int bh = b * NH + h;
                const int u = slot[bh * LSEQ + lloc];
                dl[h][threadIdx.x] = delta[((size_t)bh * NTOP + u) * DHD + threadIdx.x];
            }
        }
    }
    __syncthreads();

    const int n4 = threadIdx.x;
    float4 val = *reinterpret_cast<const float4*>(meanout + b * DMODEL + n4 * 4);
    unsigned mm = mask;
    while (mm) {
        const int h = __ffs(mm) - 1;
        mm &= mm - 1;
#pragma unroll
        for (int c = 0; c < 4; ++c) {
            const int n = n4 * 4 + c;
            const float4* wr4 = reinterpret_cast<const float4*>(
                Wo + (size_t)n * DMODEL + h * DHD);
            float a = 0.f;
#pragma unroll
            for (int dd = 0; dd < 16; ++dd) {
                const float4 wv = wr4[dd];
                a += dl[h][dd * 4 + 0] * wv.x + dl[h][dd * 4 + 1] * wv.y +
                     dl[h][dd * 4 + 2] * wv.z + dl[h][dd * 4 + 3] * wv.w;
            }
            (&val.x)[c] += a;
        }
    }
    *reinterpret_cast<float4*>(out + (size_t)rowg * DMODEL + n4 * 4) = val;
}

// ---------------------------------------------------------------------------
extern "C" void kernel_launch(void* const* d_in, const int* in_sizes, int n_in,
                              void* d_out, int out_size, void* d_ws, size_t ws_size,
                              hipStream_t stream)
{
    (void)in_sizes; (void)n_in; (void)out_size; (void)ws_size;
    const float* x     = (const float*)d_in[0];
    const float* ctxin = (const float*)d_in[1];
    const float* Wq    = (const float*)d_in[2];
    const float* bq    = (const float*)d_in[3];
    const float* Wk    = (const float*)d_in[4];
    const float* bk    = (const float*)d_in[5];
    const float* Wv    = (const float*)d_in[6];
    const float* bv    = (const float*)d_in[7];
    const float* Wo    = (const float*)d_in[8];
    const float* bo    = (const float*)d_in[9];
    const int*   idxs  = (const int*)d_in[10];
    float* out = (float*)d_out;

    char* ws = (char*)d_ws;
    size_t off = 0;
    auto alloc = [&](size_t bytes) -> void* {
        void* p = ws + off;
        off += (bytes + 255) & ~(size_t)255;
        return p;
    };

    const size_t qkv_bytes = (size_t)BATCH * NH * LSEQ * DHD * sizeof(float);
    float*         Qt       = (float*)alloc(qkv_bytes);
    float*         Kt       = (float*)alloc(qkv_bytes);
    float*         Vt       = (float*)alloc(qkv_bytes);
    float*         Mbuf     = (float*)alloc((size_t)BATCH * NH * LSEQ * sizeof(float));
    float*         VmeanRaw = (float*)alloc((size_t)BATCH * NH * DHD * sizeof(float));
    float*         meanout  = (float*)alloc((size_t)BATCH * DMODEL * sizeof(float));
    float*         delta    = (float*)alloc((size_t)BATCH * NH * NTOP * DHD * sizeof(float));
    int*           topidx   = (int*)alloc((size_t)BATCH * NH * NTOP * sizeof(int));
    unsigned*      headmask = (unsigned*)alloc((size_t)BATCH * LSEQ * sizeof(unsigned));
    unsigned char* slot     = (unsigned char*)alloc((size_t)BATCH * NH * LSEQ);
    float*         psums    = (float*)alloc((size_t)BATCH * NH * NCHUNK * NTOP * sizeof(float));
    u16*           xsP      = (u16*)alloc(ASTRIDE * 3 * 2);
    u16*           csP      = (u16*)alloc(ASTRIDE * 3 * 2);
    u16*           wqP      = (u16*)alloc(WSTRIDE * 3 * 2);
    u16*           wkP      = (u16*)alloc(WSTRIDE * 3 * 2);
    u16*           wvP      = (u16*)alloc(WSTRIDE * 3 * 2);
    // pacc (10.5 MB) aliases xsP planes: x-planes dead after qkv_gemm_mfma,
    // and attn_partial runs strictly after it.
    float*         pacc     = (float*)xsP;

    split3_all<<<2048, 256, 0, stream>>>(x, ctxin, Wq, Wk, Wv,
                                         xsP, csP, wqP, wkP, wvP);

    qkv_gemm_mfma<<<dim3(256, 3), 256, 0, stream>>>(
        xsP, csP, wqP, wkP, wvP, bq, bk, bv, Qt, Kt, Vt);

    score_kernel<<<(BATCH * NH * LSEQ) / 4, 256, 0, stream>>>(
        Qt, Kt, idxs, Mbuf, headmask, VmeanRaw);

    topk_kernel<<<BATCH * NH, 256, 0, stream>>>(Mbuf, topidx, headmask, slot);

    attn_partial<<<dim3(BATCH * NH, NCHUNK), 256, 0, stream>>>(
        Qt, Kt, Vt, topidx, psums, pacc, VmeanRaw);

    attn_combine<<<dim3(BATCH * NH, 4), 256, 0, stream>>>(
        psums, pacc, VmeanRaw, Wo, bo, delta, meanout);

    out_kernel<<<BATCH * LSEQ, 128, 0, stream>>>(
        meanout, headmask, slot, delta, Wo, out);
}